// Round 2
// baseline (519.076 us; speedup 1.0000x reference)
//
#include <hip/hip_runtime.h>
#include <hip/hip_bf16.h>

// Problem constants (B,L,H,D) = (8,2048,8,64); sample_k = u = 40.
#define BB 8
#define LL 2048
#define HH 8
#define DD 64
#define HD 512      // H*D
#define SK 40       // sample_k
#define UU 40       // top-u
#define NCHUNK 16   // key chunks for flash-decode
#define CHUNK 128   // keys per chunk
#define UT 20       // u-tile per kE block (2 tiles)
#define KSTR 68     // padded Ks row stride (floats), 16B-aligned, breaks 64-stride conflicts

// ---------------- workspace layout (bytes) ----------------
static const size_t OFF_M     = 0;                 // B*H*L floats   = 512 KB
static const size_t OFF_TOP   = 512ull * 1024;     // B*H*40 ints    = 10 KB
static const size_t OFF_VMEAN = 576ull * 1024;     // B*H*64 floats  = 16 KB
static const size_t OFF_VPART = 592ull * 1024;     // 8*B*H*64 floats= 128 KB
static const size_t OFF_MPART = 768ull * 1024;     // B*H*40*16      = 160 KB
static const size_t OFF_SPART = 960ull * 1024;     // B*H*40*16      = 160 KB
static const size_t OFF_OPART = 1152ull * 1024;    // B*H*40*16*64   = 10 MB

// ============ kernel A: M[b,h,q] = max_s(Q.Ksample) - mean_s(Q.Ksample) ============
// block = 128 = 8 heads x 16 lanes (float4/lane). one block per (b,q).
// indices are wave-uniform -> scalar loads; gathers batched 8-deep for MLP.
__global__ __launch_bounds__(128) void kA_sample_scores(
    const float* __restrict__ Q, const float* __restrict__ K,
    const int* __restrict__ IS, float* __restrict__ M)
{
    int blk = blockIdx.x;            // b*L + q
    int b = blk >> 11;
    int q = blk & (LL - 1);
    int tid = threadIdx.x;
    int h = tid >> 4;
    int lane = tid & 15;

    const int* __restrict__ isq = IS + q * SK;   // uniform -> s_load
    size_t base = (size_t)b * LL * HD;
    int off = h * DD + lane * 4;
    const float4 qv = *(const float4*)(Q + base + (size_t)q * HD + off);
    const float* __restrict__ Kb = K + base + off;

    float mx = -1e30f, sm = 0.f;
#pragma unroll
    for (int s0 = 0; s0 < SK; s0 += 8) {
        float4 kv[8];
#pragma unroll
        for (int j = 0; j < 8; ++j)
            kv[j] = *(const float4*)(Kb + (size_t)isq[s0 + j] * HD);
#pragma unroll
        for (int j = 0; j < 8; ++j) {
            float p = qv.x * kv[j].x + qv.y * kv[j].y + qv.z * kv[j].z + qv.w * kv[j].w;
            p += __shfl_xor(p, 1);
            p += __shfl_xor(p, 2);
            p += __shfl_xor(p, 4);
            p += __shfl_xor(p, 8);
            mx = fmaxf(mx, p);
            sm += p;
        }
    }
    if (lane == 0)
        M[((size_t)(b * HH + h)) * LL + q] = mx - sm * (1.0f / SK);
}

// ============ kernel B: top-40 of M[bh,:] via 12-bit radix select ============
// Only the SET of top-40 indices matters (each selected row's output is
// order-independent), so no sorted output needed.
__global__ __launch_bounds__(256) void kB_topk(
    const float* __restrict__ M, int* __restrict__ TopIdx)
{
    int bh = blockIdx.x;
    int tid = threadIdx.x;
    __shared__ unsigned keys[LL];       // 8 KB
    __shared__ unsigned hist[4096];     // 16 KB
    __shared__ unsigned cand_key[2048]; // 8 KB
    __shared__ int      cand_idx[2048]; // 8 KB
    __shared__ int counters[4];         // selCnt, candCnt, T, kprime

    const float* __restrict__ m = M + (size_t)bh * LL;
    for (int i = tid; i < 4096; i += 256) hist[i] = 0;
    if (tid < 4) counters[tid] = 0;
    __syncthreads();

    for (int i = tid; i < LL; i += 256) {
        unsigned u = __float_as_uint(m[i]);
        u = (u & 0x80000000u) ? ~u : (u | 0x80000000u);   // monotone key
        keys[i] = u;
        atomicAdd(&hist[u >> 20], 1u);
    }
    __syncthreads();

    if (tid == 0) {
        int cum = 0;
        for (int bkt = 4095; bkt >= 0; --bkt) {
            int c = (int)hist[bkt];
            if (cum + c >= UU) { counters[2] = bkt; counters[3] = UU - cum; break; }
            cum += c;
        }
    }
    __syncthreads();
    unsigned T = (unsigned)counters[2];

    for (int i = tid; i < LL; i += 256) {
        unsigned u = keys[i];
        unsigned bkt = u >> 20;
        if (bkt > T) {
            int p = atomicAdd(&counters[0], 1);
            TopIdx[bh * UU + p] = i;
        } else if (bkt == T) {
            int p = atomicAdd(&counters[1], 1);
            cand_key[p] = u; cand_idx[p] = i;
        }
    }
    __syncthreads();

    if (tid == 0) {
        int kprime = counters[3];
        int n = counters[1];
        int basep = counters[0];
        for (int r = 0; r < kprime; ++r) {
            unsigned bk = 0; int bi = 1 << 30; int bp = -1;
            for (int j = 0; j < n; ++j) {
                int id = cand_idx[j];
                if (id < 0) continue;
                unsigned k2 = cand_key[j];
                if (k2 > bk || (k2 == bk && id < bi)) { bk = k2; bi = id; bp = j; }
            }
            TopIdx[bh * UU + basep + r] = bi;
            cand_idx[bp] = -1;
        }
    }
}

// ============ kernel C: V partial column-sums (no atomics) ============
__global__ __launch_bounds__(256) void kC_vmean(
    const float* __restrict__ V, float* __restrict__ Vpart)
{
    int bh = blockIdx.x >> 3;        // 0..63
    int ch = blockIdx.x & 7;         // 8 chunks of 256 rows
    int b = bh >> 3, h = bh & 7;
    int tid = threadIdx.x;
    int d = tid & 63, lg = tid >> 6; // 4 row-groups

    float s = 0.f;
    size_t base = ((size_t)b * LL + ch * 256) * HD + h * DD + d;
    for (int l = lg; l < 256; l += 4) s += V[base + (size_t)l * HD];

    __shared__ float red[256];
    red[tid] = s;
    __syncthreads();
    if (tid < 64) {
        float t = red[tid] + red[tid + 64] + red[tid + 128] + red[tid + 192];
        Vpart[ch * (64 * 64) + bh * 64 + tid] = t;
    }
}

// ============ kernel Cr: reduce 8 partials -> Vmean ============
__global__ __launch_bounds__(256) void kCr_reduce(
    const float* __restrict__ Vpart, float* __restrict__ Vmean)
{
    int i = blockIdx.x * 256 + threadIdx.x;  // 0..4095
    float s = 0.f;
#pragma unroll
    for (int c = 0; c < 8; ++c) s += Vpart[c * 4096 + i];
    Vmean[i] = s;
}

// ============ kernel D: fill all output rows with Vmean/L ============
__global__ __launch_bounds__(256) void kD_fill(
    const float* __restrict__ Vmean, float* __restrict__ out)
{
    size_t i4 = (size_t)blockIdx.x * 256 + threadIdx.x; // float4 index
    size_t o = i4 * 4;
    int hd = (int)(o & (HD - 1));
    int b  = (int)(o >> 20);         // / (L*HD) = 2^20
    int h  = hd >> 6;
    float4 v = *(const float4*)(Vmean + (b * HH + h) * DD + (hd & 63));
    const float sc = 1.0f / LL;
    float4 r; r.x = v.x * sc; r.y = v.y * sc; r.z = v.z * sc; r.w = v.w * sc;
    *(float4*)(out + o) = r;
}

// ============ kernel E: flash-decode partials, u split in 2 tiles of 20 ============
// grid = (NCHUNK, B*H, 2), block = 256
__global__ __launch_bounds__(256) void kE_attn_partial(
    const float* __restrict__ Q, const float* __restrict__ K, const float* __restrict__ V,
    const int* __restrict__ TopIdx,
    float* __restrict__ Opart, float* __restrict__ mpart, float* __restrict__ spart)
{
    int c  = blockIdx.x;   // key chunk
    int bh = blockIdx.y;
    int ut = blockIdx.z;   // u-tile (0/1)
    int b = bh >> 3, h = bh & 7;
    int tid = threadIdx.x;

    __shared__ float Qs[UT * DD];            // 5 KB
    __shared__ float Ks[CHUNK * KSTR];       // 34 KB (reused for V)
    __shared__ float P[CHUNK * (UT + 1)];    // 10.5 KB
    __shared__ int   qidx[UT];
    __shared__ float mred[UT], sred[UT];

    if (tid < UT) qidx[tid] = TopIdx[bh * UU + ut * UT + tid];
    __syncthreads();

    size_t hbase  = (size_t)b * LL * HD + h * DD;
    size_t kcbase = hbase + (size_t)c * CHUNK * HD;

    // stage Q rows (20x64) and K chunk (128x64, padded stride)
    for (int r = tid; r < UT * 16; r += 256) {
        int u = r >> 4, j = r & 15;
        *(float4*)(Qs + u * DD + j * 4) =
            *(const float4*)(Q + hbase + (size_t)qidx[u] * HD + j * 4);
    }
    for (int r = tid; r < CHUNK * 16; r += 256) {
        int l = r >> 4, j = r & 15;
        *(float4*)(Ks + l * KSTR + j * 4) =
            *(const float4*)(K + kcbase + (size_t)l * HD + j * 4);
    }
    __syncthreads();

    // scores: l = tid&127, ug = tid>>7; K row in regs, reused for 10 u's
    {
        int l = tid & (CHUNK - 1), ug = tid >> 7;
        float4 kr[16];
#pragma unroll
        for (int j = 0; j < 16; ++j) kr[j] = *(const float4*)(Ks + l * KSTR + j * 4);
#pragma unroll 2
        for (int uu = 0; uu < 10; ++uu) {
            int u = ug * 10 + uu;
            float dot = 0.f;
#pragma unroll
            for (int j = 0; j < 16; ++j) {
                float4 qv = *(const float4*)(Qs + u * DD + j * 4);
                dot += qv.x * kr[j].x + qv.y * kr[j].y + qv.z * kr[j].z + qv.w * kr[j].w;
            }
            P[l * (UT + 1) + u] = dot * 0.125f;  // 1/sqrt(64)
        }
    }
    __syncthreads();

    // per-u chunk max (20 u x 8 parts = 160 threads)
    if (tid < UT * 8) {
        int u = tid >> 3, part = tid & 7;
        float m = -1e30f;
        for (int l = part * 16; l < part * 16 + 16; ++l) m = fmaxf(m, P[l * (UT + 1) + u]);
        m = fmaxf(m, __shfl_xor(m, 1));
        m = fmaxf(m, __shfl_xor(m, 2));
        m = fmaxf(m, __shfl_xor(m, 4));
        if (part == 0) mred[u] = m;
    }
    __syncthreads();
    // exp + per-u chunk sum
    if (tid < UT * 8) {
        int u = tid >> 3, part = tid & 7;
        float m = mred[u];
        float s = 0.f;
        for (int l = part * 16; l < part * 16 + 16; ++l) {
            float p = __expf(P[l * (UT + 1) + u] - m);
            P[l * (UT + 1) + u] = p;
            s += p;
        }
        s += __shfl_xor(s, 1);
        s += __shfl_xor(s, 2);
        s += __shfl_xor(s, 4);
        if (part == 0) sred[u] = s;
    }
    __syncthreads();

    // stage V chunk into Ks buffer
    for (int r = tid; r < CHUNK * 16; r += 256) {
        int l = r >> 4, j = r & 15;
        *(float4*)(Ks + l * KSTR + j * 4) =
            *(const float4*)(V + kcbase + (size_t)l * HD + j * 4);
    }
    __syncthreads();

    // PV: d2 = tid&31 (2 d's), ug2 = tid>>5 (u = ug2 + 8i, guard u<20)
    {
        int d2 = tid & 31, ug2 = tid >> 5;
        float acc[3][2];
#pragma unroll
        for (int i = 0; i < 3; ++i) { acc[i][0] = 0.f; acc[i][1] = 0.f; }
        for (int l = 0; l < CHUNK; ++l) {
            float v0 = Ks[l * KSTR + d2 * 2];
            float v1 = Ks[l * KSTR + d2 * 2 + 1];
#pragma unroll
            for (int i = 0; i < 3; ++i) {
                int u = ug2 + i * 8;
                if (u < UT) {
                    float p = P[l * (UT + 1) + u];
                    acc[i][0] += p * v0;
                    acc[i][1] += p * v1;
                }
            }
        }
#pragma unroll
        for (int i = 0; i < 3; ++i) {
            int u = ug2 + i * 8;
            if (u < UT) {
                int ug_ = ut * UT + u;
                size_t ob = (((size_t)(bh * UU + ug_)) * NCHUNK + c) * DD + d2 * 2;
                float2 st; st.x = acc[i][0]; st.y = acc[i][1];
                *(float2*)(Opart + ob) = st;
            }
        }
    }
    if (tid < UT) {
        int ug_ = ut * UT + tid;
        mpart[(bh * UU + ug_) * NCHUNK + c] = mred[tid];
        spart[(bh * UU + ug_) * NCHUNK + c] = sred[tid];
    }
}

// ============ kernel F: combine chunk partials, scatter into output ============
__global__ __launch_bounds__(64) void kF_combine(
    const float* __restrict__ Opart, const float* __restrict__ mpart,
    const float* __restrict__ spart, const int* __restrict__ TopIdx,
    float* __restrict__ out)
{
    int g = blockIdx.x;            // bh*40 + u
    int bh = g / UU;
    int b = bh >> 3, h = bh & 7;
    int d = threadIdx.x;

    float m_i[NCHUNK];
    float Mx = -1e30f;
#pragma unroll
    for (int i = 0; i < NCHUNK; ++i) { m_i[i] = mpart[g * NCHUNK + i]; Mx = fmaxf(Mx, m_i[i]); }
    float S = 0.f, O = 0.f;
#pragma unroll
    for (int i = 0; i < NCHUNK; ++i) {
        float w = __expf(m_i[i] - Mx);
        S += w * spart[g * NCHUNK + i];
        O += w * Opart[((size_t)g * NCHUNK + i) * DD + d];
    }
    int qi = TopIdx[g];
    out[((size_t)b * LL + qi) * HD + h * DD + d] = O / S;
}

extern "C" void kernel_launch(void* const* d_in, const int* in_sizes, int n_in,
                              void* d_out, int out_size, void* d_ws, size_t ws_size,
                              hipStream_t stream) {
    const float* Q  = (const float*)d_in[0];
    const float* K  = (const float*)d_in[1];
    const float* V  = (const float*)d_in[2];
    const int*   IS = (const int*)d_in[3];
    float* out = (float*)d_out;
    char* ws = (char*)d_ws;

    float* M      = (float*)(ws + OFF_M);
    int*   TopIdx = (int*)(ws + OFF_TOP);
    float* Vmean  = (float*)(ws + OFF_VMEAN);
    float* Vpart  = (float*)(ws + OFF_VPART);
    float* mpart  = (float*)(ws + OFF_MPART);
    float* spart  = (float*)(ws + OFF_SPART);
    float* Opart  = (float*)(ws + OFF_OPART);

    kA_sample_scores<<<BB * LL, 128, 0, stream>>>(Q, K, IS, M);
    kC_vmean<<<BB * HH * 8, 256, 0, stream>>>(V, Vpart);
    kCr_reduce<<<16, 256, 0, stream>>>(Vpart, Vmean);
    kB_topk<<<BB * HH, 256, 0, stream>>>(M, TopIdx);
    kD_fill<<<(BB * LL * HD) / (256 * 4), 256, 0, stream>>>(Vmean, out);
    kE_attn_partial<<<dim3(NCHUNK, BB * HH, 2), 256, 0, stream>>>(Q, K, V, TopIdx,
                                                                  Opart, mpart, spart);
    kF_combine<<<BB * HH * UU, 64, 0, stream>>>(Opart, mpart, spart, TopIdx, out);
}

// Round 3
// 438.679 us; speedup vs baseline: 1.1833x; 1.1833x over previous
//
#include <hip/hip_runtime.h>
#include <hip/hip_bf16.h>

// Problem constants (B,L,H,D) = (8,2048,8,64); sample_k = u = 40.
#define BB 8
#define LL 2048
#define HH 8
#define DD 64
#define HD 512      // H*D
#define SK 40       // sample_k
#define UU 40       // top-u
#define NCHUNK 16   // key chunks for flash-decode
#define CHUNK 128   // keys per chunk
#define UT 20       // u-tile per kE block (2 tiles)
#define KSTR 68     // padded Ks row stride (floats)

// ---------------- workspace layout (bytes) ----------------
static const size_t OFF_M     = 0;                 // B*H*L floats   = 512 KB
static const size_t OFF_TOP   = 512ull * 1024;     // B*H*40 ints    = 10 KB
static const size_t OFF_VPART = 592ull * 1024;     // 8*B*H*64 floats= 128 KB
static const size_t OFF_MPART = 768ull * 1024;     // B*H*40*16      = 160 KB
static const size_t OFF_SPART = 960ull * 1024;     // B*H*40*16      = 160 KB
static const size_t OFF_OPART = 1152ull * 1024;    // B*H*40*16*64   = 10 MB

// ============ kernel A: M[b,h,q] = max_s(Q.Ksample) - mean_s(Q.Ksample) ============
// block = 128 = 8 heads x 16 lanes (float4/lane). one block per (b,q).
// XCD-pinning: b = blockIdx & 7 -> all blocks of batch b land on XCD b
// (HW round-robins consecutive blockIdx across the 8 XCDs), so each XCD's
// gather working set is K[b] = 4 MB = its private L2 size.
__global__ __launch_bounds__(128) void kA_sample_scores(
    const float* __restrict__ Q, const float* __restrict__ K,
    const int* __restrict__ IS, float* __restrict__ M)
{
    int blk = blockIdx.x;
    int b = blk & 7;
    int q = blk >> 3;
    int tid = threadIdx.x;
    int h = tid >> 4;
    int lane = tid & 15;

    const int* __restrict__ isq = IS + q * SK;   // wave-uniform -> s_load
    size_t base = (size_t)b * LL * HD;
    int off = h * DD + lane * 4;
    const float4 qv = *(const float4*)(Q + base + (size_t)q * HD + off);
    const float* __restrict__ Kb = K + base + off;

    float mx = -1e30f, sm = 0.f;
#pragma unroll
    for (int s0 = 0; s0 < SK; s0 += 8) {
        float4 kv[8];
#pragma unroll
        for (int j = 0; j < 8; ++j)
            kv[j] = *(const float4*)(Kb + (size_t)isq[s0 + j] * HD);
#pragma unroll
        for (int j = 0; j < 8; ++j) {
            float p = qv.x * kv[j].x + qv.y * kv[j].y + qv.z * kv[j].z + qv.w * kv[j].w;
            p += __shfl_xor(p, 1);
            p += __shfl_xor(p, 2);
            p += __shfl_xor(p, 4);
            p += __shfl_xor(p, 8);
            mx = fmaxf(mx, p);
            sm += p;
        }
    }
    if (lane == 0)
        M[((size_t)(b * HH + h)) * LL + q] = mx - sm * (1.0f / SK);
}

// ============ kernel B: top-40 of M[bh,:] via 12-bit radix select ============
// Threshold search fully parallel: 256 threads x 16-bin partials + suffix scan.
__global__ __launch_bounds__(256) void kB_topk(
    const float* __restrict__ M, int* __restrict__ TopIdx)
{
    int bh = blockIdx.x;
    int tid = threadIdx.x;
    __shared__ unsigned keys[LL];       // 8 KB
    __shared__ unsigned hist[4096];     // 16 KB
    __shared__ int      sscan[256];     // 1 KB suffix sums of 16-bin partials
    __shared__ unsigned cand_key[2048]; // 8 KB
    __shared__ int      cand_idx[2048]; // 8 KB
    __shared__ int counters[4];         // selCnt, candCnt, T, kprime

    const float* __restrict__ m = M + (size_t)bh * LL;
    for (int i = tid; i < 4096; i += 256) hist[i] = 0;
    if (tid < 4) counters[tid] = 0;
    __syncthreads();

    for (int i = tid; i < LL; i += 256) {
        unsigned u = __float_as_uint(m[i]);
        u = (u & 0x80000000u) ? ~u : (u | 0x80000000u);   // monotone key
        keys[i] = u;
        atomicAdd(&hist[u >> 20], 1u);
    }
    __syncthreads();

    // partial sums: thread t owns buckets [16t, 16t+16)
    {
        int p = 0;
#pragma unroll
        for (int j = 0; j < 16; ++j) p += (int)hist[tid * 16 + j];
        sscan[tid] = p;
        __syncthreads();
        // Hillis-Steele inclusive SUFFIX scan
        for (int offs = 1; offs < 256; offs <<= 1) {
            int v = (tid + offs < 256) ? sscan[tid + offs] : 0;
            __syncthreads();
            sscan[tid] += v;
            __syncthreads();
        }
        // exactly one thread satisfies: sscan[t] >= UU and sscan[t+1] < UU
        int snext = (tid < 255) ? sscan[tid + 1] : 0;
        if (sscan[tid] >= UU && snext < UU) {
            int cum = snext;
            for (int bkt = tid * 16 + 15; bkt >= tid * 16; --bkt) {
                int c = (int)hist[bkt];
                if (cum + c >= UU) {
                    counters[2] = bkt;
                    counters[3] = UU - cum;
                    break;
                }
                cum += c;
            }
        }
    }
    __syncthreads();
    unsigned T = (unsigned)counters[2];

    for (int i = tid; i < LL; i += 256) {
        unsigned u = keys[i];
        unsigned bkt = u >> 20;
        if (bkt > T) {
            int p = atomicAdd(&counters[0], 1);
            TopIdx[bh * UU + p] = i;
        } else if (bkt == T) {
            int p = atomicAdd(&counters[1], 1);
            cand_key[p] = u; cand_idx[p] = i;
        }
    }
    __syncthreads();

    // resolve boundary bucket (n is typically tiny: one 12-bit bucket's worth)
    if (tid == 0) {
        int kprime = counters[3];
        int n = counters[1];
        int basep = counters[0];
        for (int r = 0; r < kprime; ++r) {
            unsigned bk = 0; int bi = 1 << 30; int bp = -1;
            for (int j = 0; j < n; ++j) {
                int id = cand_idx[j];
                if (id < 0) continue;
                unsigned k2 = cand_key[j];
                if (k2 > bk || (k2 == bk && id < bi)) { bk = k2; bi = id; bp = j; }
            }
            TopIdx[bh * UU + basep + r] = bi;
            cand_idx[bp] = -1;
        }
    }
}

// ============ kernel C: V partial column-sums (no atomics) ============
__global__ __launch_bounds__(256) void kC_vmean(
    const float* __restrict__ V, float* __restrict__ Vpart)
{
    int bh = blockIdx.x >> 3;        // 0..63
    int ch = blockIdx.x & 7;         // 8 chunks of 256 rows
    int b = bh >> 3, h = bh & 7;
    int tid = threadIdx.x;
    int d = tid & 63, lg = tid >> 6; // 4 row-groups

    float s = 0.f;
    size_t base = ((size_t)b * LL + ch * 256) * HD + h * DD + d;
    for (int l = lg; l < 256; l += 4) s += V[base + (size_t)l * HD];

    __shared__ float red[256];
    red[tid] = s;
    __syncthreads();
    if (tid < 64) {
        float t = red[tid] + red[tid + 64] + red[tid + 128] + red[tid + 192];
        Vpart[ch * (64 * 64) + bh * 64 + tid] = t;
    }
}

// ============ kernel D: fill all output rows with mean(V)/L (reads Vpart) ============
__global__ __launch_bounds__(256) void kD_fill(
    const float* __restrict__ Vpart, float* __restrict__ out)
{
    size_t i4 = (size_t)blockIdx.x * 256 + threadIdx.x; // float4 index
    size_t o = i4 * 4;
    int hd = (int)(o & (HD - 1));
    int b  = (int)(o >> 20);         // / (L*HD) = 2^20
    int h  = hd >> 6;
    int idx = (b * HH + h) * DD + (hd & 63);
    float4 acc = make_float4(0.f, 0.f, 0.f, 0.f);
#pragma unroll
    for (int c = 0; c < 8; ++c) {
        float4 v = *(const float4*)(Vpart + c * 4096 + idx);
        acc.x += v.x; acc.y += v.y; acc.z += v.z; acc.w += v.w;
    }
    const float sc = 1.0f / LL;
    float4 r; r.x = acc.x * sc; r.y = acc.y * sc; r.z = acc.z * sc; r.w = acc.w * sc;
    *(float4*)(out + o) = r;
}

// ============ kernel E: flash-decode partials, u split in 2 tiles of 20 ============
// grid = (NCHUNK, B*H, 2), block = 256
__global__ __launch_bounds__(256) void kE_attn_partial(
    const float* __restrict__ Q, const float* __restrict__ K, const float* __restrict__ V,
    const int* __restrict__ TopIdx,
    float* __restrict__ Opart, float* __restrict__ mpart, float* __restrict__ spart)
{
    int c  = blockIdx.x;   // key chunk
    int bh = blockIdx.y;
    int ut = blockIdx.z;   // u-tile (0/1)
    int b = bh >> 3, h = bh & 7;
    int tid = threadIdx.x;

    __shared__ float Qs[UT * DD];            // 5 KB
    __shared__ float Ks[CHUNK * KSTR];       // 34 KB (reused for V)
    __shared__ float P[CHUNK * (UT + 1)];    // 10.5 KB
    __shared__ int   qidx[UT];
    __shared__ float mred[UT], sred[UT];

    if (tid < UT) qidx[tid] = TopIdx[bh * UU + ut * UT + tid];
    __syncthreads();

    size_t hbase  = (size_t)b * LL * HD + h * DD;
    size_t kcbase = hbase + (size_t)c * CHUNK * HD;

    for (int r = tid; r < UT * 16; r += 256) {
        int u = r >> 4, j = r & 15;
        *(float4*)(Qs + u * DD + j * 4) =
            *(const float4*)(Q + hbase + (size_t)qidx[u] * HD + j * 4);
    }
    for (int r = tid; r < CHUNK * 16; r += 256) {
        int l = r >> 4, j = r & 15;
        *(float4*)(Ks + l * KSTR + j * 4) =
            *(const float4*)(K + kcbase + (size_t)l * HD + j * 4);
    }
    __syncthreads();

    // scores: l = tid&127, ug = tid>>7; K row in regs, reused for 10 u's
    {
        int l = tid & (CHUNK - 1), ug = tid >> 7;
        float4 kr[16];
#pragma unroll
        for (int j = 0; j < 16; ++j) kr[j] = *(const float4*)(Ks + l * KSTR + j * 4);
#pragma unroll 2
        for (int uu = 0; uu < 10; ++uu) {
            int u = ug * 10 + uu;
            float dot = 0.f;
#pragma unroll
            for (int j = 0; j < 16; ++j) {
                float4 qv = *(const float4*)(Qs + u * DD + j * 4);
                dot += qv.x * kr[j].x + qv.y * kr[j].y + qv.z * kr[j].z + qv.w * kr[j].w;
            }
            P[l * (UT + 1) + u] = dot * 0.125f;  // 1/sqrt(64)
        }
    }
    __syncthreads();

    // per-u chunk max (20 u x 8 parts = 160 threads)
    if (tid < UT * 8) {
        int u = tid >> 3, part = tid & 7;
        float m = -1e30f;
        for (int l = part * 16; l < part * 16 + 16; ++l) m = fmaxf(m, P[l * (UT + 1) + u]);
        m = fmaxf(m, __shfl_xor(m, 1));
        m = fmaxf(m, __shfl_xor(m, 2));
        m = fmaxf(m, __shfl_xor(m, 4));
        if (part == 0) mred[u] = m;
    }
    __syncthreads();
    if (tid < UT * 8) {
        int u = tid >> 3, part = tid & 7;
        float m = mred[u];
        float s = 0.f;
        for (int l = part * 16; l < part * 16 + 16; ++l) {
            float p = __expf(P[l * (UT + 1) + u] - m);
            P[l * (UT + 1) + u] = p;
            s += p;
        }
        s += __shfl_xor(s, 1);
        s += __shfl_xor(s, 2);
        s += __shfl_xor(s, 4);
        if (part == 0) sred[u] = s;
    }
    __syncthreads();

    for (int r = tid; r < CHUNK * 16; r += 256) {
        int l = r >> 4, j = r & 15;
        *(float4*)(Ks + l * KSTR + j * 4) =
            *(const float4*)(V + kcbase + (size_t)l * HD + j * 4);
    }
    __syncthreads();

    // PV: d2 = tid&31 (2 d's), ug2 = tid>>5 (u = ug2 + 8i, guard u<20)
    {
        int d2 = tid & 31, ug2 = tid >> 5;
        float acc[3][2];
#pragma unroll
        for (int i = 0; i < 3; ++i) { acc[i][0] = 0.f; acc[i][1] = 0.f; }
        for (int l = 0; l < CHUNK; ++l) {
            float v0 = Ks[l * KSTR + d2 * 2];
            float v1 = Ks[l * KSTR + d2 * 2 + 1];
#pragma unroll
            for (int i = 0; i < 3; ++i) {
                int u = ug2 + i * 8;
                if (u < UT) {
                    float p = P[l * (UT + 1) + u];
                    acc[i][0] += p * v0;
                    acc[i][1] += p * v1;
                }
            }
        }
#pragma unroll
        for (int i = 0; i < 3; ++i) {
            int u = ug2 + i * 8;
            if (u < UT) {
                int ug_ = ut * UT + u;
                size_t ob = (((size_t)(bh * UU + ug_)) * NCHUNK + c) * DD + d2 * 2;
                float2 st; st.x = acc[i][0]; st.y = acc[i][1];
                *(float2*)(Opart + ob) = st;
            }
        }
    }
    if (tid < UT) {
        int ug_ = ut * UT + tid;
        mpart[(bh * UU + ug_) * NCHUNK + c] = mred[tid];
        spart[(bh * UU + ug_) * NCHUNK + c] = sred[tid];
    }
}

// ============ kernel F: combine chunk partials, scatter into output ============
__global__ __launch_bounds__(64) void kF_combine(
    const float* __restrict__ Opart, const float* __restrict__ mpart,
    const float* __restrict__ spart, const int* __restrict__ TopIdx,
    float* __restrict__ out)
{
    int g = blockIdx.x;            // bh*40 + u
    int bh = g / UU;
    int b = bh >> 3, h = bh & 7;
    int d = threadIdx.x;

    float m_i[NCHUNK];
    float Mx = -1e30f;
#pragma unroll
    for (int i = 0; i < NCHUNK; ++i) { m_i[i] = mpart[g * NCHUNK + i]; Mx = fmaxf(Mx, m_i[i]); }
    float S = 0.f, O = 0.f;
#pragma unroll
    for (int i = 0; i < NCHUNK; ++i) {
        float w = __expf(m_i[i] - Mx);
        S += w * spart[g * NCHUNK + i];
        O += w * Opart[((size_t)g * NCHUNK + i) * DD + d];
    }
    int qi = TopIdx[g];
    out[((size_t)b * LL + qi) * HD + h * DD + d] = O / S;
}

extern "C" void kernel_launch(void* const* d_in, const int* in_sizes, int n_in,
                              void* d_out, int out_size, void* d_ws, size_t ws_size,
                              hipStream_t stream) {
    const float* Q  = (const float*)d_in[0];
    const float* K  = (const float*)d_in[1];
    const float* V  = (const float*)d_in[2];
    const int*   IS = (const int*)d_in[3];
    float* out = (float*)d_out;
    char* ws = (char*)d_ws;

    float* M      = (float*)(ws + OFF_M);
    int*   TopIdx = (int*)(ws + OFF_TOP);
    float* Vpart  = (float*)(ws + OFF_VPART);
    float* mpart  = (float*)(ws + OFF_MPART);
    float* spart  = (float*)(ws + OFF_SPART);
    float* Opart  = (float*)(ws + OFF_OPART);

    kA_sample_scores<<<BB * LL, 128, 0, stream>>>(Q, K, IS, M);
    kC_vmean<<<BB * HH * 8, 256, 0, stream>>>(V, Vpart);
    kB_topk<<<BB * HH, 256, 0, stream>>>(M, TopIdx);
    kD_fill<<<(BB * LL * HD) / (256 * 4), 256, 0, stream>>>(Vpart, out);
    kE_attn_partial<<<dim3(NCHUNK, BB * HH, 2), 256, 0, stream>>>(Q, K, V, TopIdx,
                                                                  Opart, mpart, spart);
    kF_combine<<<BB * HH * UU, 64, 0, stream>>>(Opart, mpart, spart, TopIdx, out);
}

// Round 4
// 431.618 us; speedup vs baseline: 1.2026x; 1.0164x over previous
//
#include <hip/hip_runtime.h>
#include <hip/hip_bf16.h>

// Problem constants (B,L,H,D) = (8,2048,8,64); sample_k = u = 40.
#define BB 8
#define LL 2048
#define HH 8
#define DD 64
#define HD 512      // H*D
#define SK 40       // sample_k
#define UU 40       // top-u
#define NCHUNK 16   // key chunks for flash-decode
#define CHUNK 128   // keys per chunk

// ---------------- workspace layout (bytes) ----------------
static const size_t OFF_M     = 0;                 // B*H*L floats   = 512 KB
static const size_t OFF_TOP   = 512ull * 1024;     // B*H*40 ints    = 10 KB
static const size_t OFF_VPART = 592ull * 1024;     // 8*B*H*64 floats= 128 KB
static const size_t OFF_MPART = 768ull * 1024;     // B*H*40*16      = 160 KB
static const size_t OFF_SPART = 960ull * 1024;     // B*H*40*16      = 160 KB
static const size_t OFF_OPART = 1152ull * 1024;    // B*H*40*16*64   = 10 MB

// ============ kernel A: M[b,h,q] = max_s(Q.Ksample) - mean_s(Q.Ksample) ============
// ROUND-1 VERSION (proven 90 us, VGPR=32). block = 128 = 8 heads x 16 lanes.
__global__ __launch_bounds__(128) void kA_sample_scores(
    const float* __restrict__ Q, const float* __restrict__ K,
    const int* __restrict__ IS, float* __restrict__ M)
{
    int blk = blockIdx.x;            // b*L + q
    int b = blk >> 11;
    int q = blk & (LL - 1);
    int tid = threadIdx.x;
    int h = tid >> 4;
    int lane = tid & 15;

    __shared__ int sidx[SK];
    if (tid < SK) sidx[tid] = IS[q * SK + tid];
    __syncthreads();

    size_t base = (size_t)b * LL * HD;
    const float4 qv = *(const float4*)(Q + base + (size_t)q * HD + h * DD + lane * 4);

    float mx = -1e30f, sm = 0.f;
#pragma unroll 8
    for (int s = 0; s < SK; ++s) {
        int idx = sidx[s];
        const float4 kv = *(const float4*)(K + base + (size_t)idx * HD + h * DD + lane * 4);
        float p = qv.x * kv.x + qv.y * kv.y + qv.z * kv.z + qv.w * kv.w;
        p += __shfl_xor(p, 1);
        p += __shfl_xor(p, 2);
        p += __shfl_xor(p, 4);
        p += __shfl_xor(p, 8);
        mx = fmaxf(mx, p);
        sm += p;
    }
    if (lane == 0)
        M[((size_t)(b * HH + h)) * LL + q] = mx - sm * (1.0f / SK);
}

// ============ kernel B: top-40 of M[bh,:] via 12-bit radix select ============
__global__ __launch_bounds__(256) void kB_topk(
    const float* __restrict__ M, int* __restrict__ TopIdx)
{
    int bh = blockIdx.x;
    int tid = threadIdx.x;
    __shared__ unsigned keys[LL];       // 8 KB
    __shared__ unsigned hist[4096];     // 16 KB
    __shared__ int      sscan[256];     // 1 KB
    __shared__ unsigned cand_key[2048]; // 8 KB
    __shared__ int      cand_idx[2048]; // 8 KB
    __shared__ int counters[4];         // selCnt, candCnt, T, kprime

    const float* __restrict__ m = M + (size_t)bh * LL;
    for (int i = tid; i < 4096; i += 256) hist[i] = 0;
    if (tid < 4) counters[tid] = 0;
    __syncthreads();

    for (int i = tid; i < LL; i += 256) {
        unsigned u = __float_as_uint(m[i]);
        u = (u & 0x80000000u) ? ~u : (u | 0x80000000u);   // monotone key
        keys[i] = u;
        atomicAdd(&hist[u >> 20], 1u);
    }
    __syncthreads();

    {
        int p = 0;
#pragma unroll
        for (int j = 0; j < 16; ++j) p += (int)hist[tid * 16 + j];
        sscan[tid] = p;
        __syncthreads();
        for (int offs = 1; offs < 256; offs <<= 1) {
            int v = (tid + offs < 256) ? sscan[tid + offs] : 0;
            __syncthreads();
            sscan[tid] += v;
            __syncthreads();
        }
        int snext = (tid < 255) ? sscan[tid + 1] : 0;
        if (sscan[tid] >= UU && snext < UU) {
            int cum = snext;
            for (int bkt = tid * 16 + 15; bkt >= tid * 16; --bkt) {
                int c = (int)hist[bkt];
                if (cum + c >= UU) {
                    counters[2] = bkt;
                    counters[3] = UU - cum;
                    break;
                }
                cum += c;
            }
        }
    }
    __syncthreads();
    unsigned T = (unsigned)counters[2];

    for (int i = tid; i < LL; i += 256) {
        unsigned u = keys[i];
        unsigned bkt = u >> 20;
        if (bkt > T) {
            int p = atomicAdd(&counters[0], 1);
            TopIdx[bh * UU + p] = i;
        } else if (bkt == T) {
            int p = atomicAdd(&counters[1], 1);
            cand_key[p] = u; cand_idx[p] = i;
        }
    }
    __syncthreads();

    if (tid == 0) {
        int kprime = counters[3];
        int n = counters[1];
        int basep = counters[0];
        for (int r = 0; r < kprime; ++r) {
            unsigned bk = 0; int bi = 1 << 30; int bp = -1;
            for (int j = 0; j < n; ++j) {
                int id = cand_idx[j];
                if (id < 0) continue;
                unsigned k2 = cand_key[j];
                if (k2 > bk || (k2 == bk && id < bi)) { bk = k2; bi = id; bp = j; }
            }
            TopIdx[bh * UU + basep + r] = bi;
            cand_idx[bp] = -1;
        }
    }
}

// ============ kernel C: V partial column-sums ============
__global__ __launch_bounds__(256) void kC_vmean(
    const float* __restrict__ V, float* __restrict__ Vpart)
{
    int bh = blockIdx.x >> 3;
    int ch = blockIdx.x & 7;
    int b = bh >> 3, h = bh & 7;
    int tid = threadIdx.x;
    int d = tid & 63, lg = tid >> 6;

    float s = 0.f;
    size_t base = ((size_t)b * LL + ch * 256) * HD + h * DD + d;
    for (int l = lg; l < 256; l += 4) s += V[base + (size_t)l * HD];

    __shared__ float red[256];
    red[tid] = s;
    __syncthreads();
    if (tid < 64) {
        float t = red[tid] + red[tid + 64] + red[tid + 128] + red[tid + 192];
        Vpart[ch * (64 * 64) + bh * 64 + tid] = t;
    }
}

// ============ kernel D: fill all output rows with mean(V)/L ============
__global__ __launch_bounds__(256) void kD_fill(
    const float* __restrict__ Vpart, float* __restrict__ out)
{
    size_t i4 = (size_t)blockIdx.x * 256 + threadIdx.x;
    size_t o = i4 * 4;
    int hd = (int)(o & (HD - 1));
    int b  = (int)(o >> 20);
    int h  = hd >> 6;
    int idx = (b * HH + h) * DD + (hd & 63);
    float4 acc = make_float4(0.f, 0.f, 0.f, 0.f);
#pragma unroll
    for (int c = 0; c < 8; ++c) {
        float4 v = *(const float4*)(Vpart + c * 4096 + idx);
        acc.x += v.x; acc.y += v.y; acc.z += v.z; acc.w += v.w;
    }
    const float sc = 1.0f / LL;
    float4 r; r.x = acc.x * sc; r.y = acc.y * sc; r.z = acc.z * sc; r.w = acc.w * sc;
    *(float4*)(out + o) = r;
}

// ============ kernel E v3: flash-decode partials, all 40 u per block ============
// grid = (NCHUNK, B*H), block 256. NO K/V LDS staging: K rows -> regs from L2,
// V rows -> one 256B wave-read per l from L2. LDS = Q(10K) + P(21K) ~= 31.7 KB
// -> 5 blocks/CU (20 waves) vs previous 3 blocks (12 waves).
__global__ __launch_bounds__(256) void kE_attn_partial(
    const float* __restrict__ Q, const float* __restrict__ K, const float* __restrict__ V,
    const int* __restrict__ TopIdx,
    float* __restrict__ Opart, float* __restrict__ mpart, float* __restrict__ spart)
{
    int c  = blockIdx.x;
    int bh = blockIdx.y;
    int b = bh >> 3, h = bh & 7;
    int tid = threadIdx.x;

    __shared__ float Qs[UU * DD];          // 10 KB
    __shared__ float P[CHUNK * 41];        // 21 KB; bank = (9l+u)%32 -> 2-way max (free)
    __shared__ int   qidx[UU];
    __shared__ float mred[UU], sred[UU];

    if (tid < UU) qidx[tid] = TopIdx[bh * UU + tid];
    __syncthreads();

    size_t hbase  = (size_t)b * LL * HD + h * DD;
    size_t kcbase = hbase + (size_t)c * CHUNK * HD;

    // stage gathered Q rows (40x64)
    for (int r = tid; r < UU * 16; r += 256) {
        int u = r >> 4, j = r & 15;
        *(float4*)(Qs + u * DD + j * 4) =
            *(const float4*)(Q + hbase + (size_t)qidx[u] * HD + j * 4);
    }
    __syncthreads();

    // ---- scores: thread (l = tid&127, ug = tid>>7); 20 u per thread ----
    // K row direct from global (L2-hot), in 2 halves of 8 float4 to cap VGPR.
    {
        int l = tid & (CHUNK - 1), ug = tid >> 7;
        const float* __restrict__ Krow = K + kcbase + (size_t)l * HD;
        float dot[20];
#pragma unroll
        for (int i = 0; i < 20; ++i) dot[i] = 0.f;

#pragma unroll
        for (int half = 0; half < 2; ++half) {
            float4 kr[8];
#pragma unroll
            for (int j = 0; j < 8; ++j)
                kr[j] = *(const float4*)(Krow + half * 32 + j * 4);
#pragma unroll
            for (int j = 0; j < 8; ++j) {
                float4 kv = kr[j];
#pragma unroll
                for (int uu = 0; uu < 20; ++uu) {
                    float4 qv = *(const float4*)(Qs + (ug * 20 + uu) * DD + half * 32 + j * 4);
                    dot[uu] += kv.x * qv.x + kv.y * qv.y + kv.z * qv.z + kv.w * qv.w;
                }
            }
        }
#pragma unroll
        for (int uu = 0; uu < 20; ++uu)
            P[l * 41 + ug * 20 + uu] = dot[uu] * 0.125f;   // 1/sqrt(64)
    }
    __syncthreads();

    // ---- per-u chunk max (40 u x 4 parts of 32 l = 160 threads) ----
    if (tid < UU * 4) {
        int u = tid >> 2, part = tid & 3;
        float m = -1e30f;
        for (int l = part * 32; l < part * 32 + 32; ++l) m = fmaxf(m, P[l * 41 + u]);
        m = fmaxf(m, __shfl_xor(m, 1));
        m = fmaxf(m, __shfl_xor(m, 2));
        if (part == 0) mred[u] = m;
    }
    __syncthreads();
    // ---- exp + per-u chunk sum ----
    if (tid < UU * 4) {
        int u = tid >> 2, part = tid & 3;
        float m = mred[u];
        float s = 0.f;
        for (int l = part * 32; l < part * 32 + 32; ++l) {
            float p = __expf(P[l * 41 + u] - m);
            P[l * 41 + u] = p;
            s += p;
        }
        s += __shfl_xor(s, 1);
        s += __shfl_xor(s, 2);
        if (part == 0) sred[u] = s;
    }
    __syncthreads();

    // ---- PV: thread (dq = tid&15 -> d=dq*4, ug4 = tid>>4); u = ug4 + 16i ----
    // V row read straight from global: lanes 0..15 cover the full 256B row.
    {
        int dq = tid & 15, ug4 = tid >> 4;
        float4 acc[3];
#pragma unroll
        for (int i = 0; i < 3; ++i) acc[i] = make_float4(0.f, 0.f, 0.f, 0.f);
        const float* __restrict__ Vb = V + kcbase + dq * 4;
#pragma unroll 2
        for (int l = 0; l < CHUNK; ++l) {
            float4 v4 = *(const float4*)(Vb + (size_t)l * HD);
#pragma unroll
            for (int i = 0; i < 3; ++i) {
                int u = ug4 + 16 * i;
                if (u < UU) {
                    float p = P[l * 41 + u];
                    acc[i].x += p * v4.x; acc[i].y += p * v4.y;
                    acc[i].z += p * v4.z; acc[i].w += p * v4.w;
                }
            }
        }
#pragma unroll
        for (int i = 0; i < 3; ++i) {
            int u = ug4 + 16 * i;
            if (u < UU) {
                size_t ob = (((size_t)(bh * UU + u)) * NCHUNK + c) * DD + dq * 4;
                *(float4*)(Opart + ob) = acc[i];
            }
        }
    }
    if (tid < UU) {
        mpart[(bh * UU + tid) * NCHUNK + c] = mred[tid];
        spart[(bh * UU + tid) * NCHUNK + c] = sred[tid];
    }
}

// ============ kernel F: combine chunk partials, scatter into output ============
__global__ __launch_bounds__(64) void kF_combine(
    const float* __restrict__ Opart, const float* __restrict__ mpart,
    const float* __restrict__ spart, const int* __restrict__ TopIdx,
    float* __restrict__ out)
{
    int g = blockIdx.x;            // bh*40 + u
    int bh = g / UU;
    int b = bh >> 3, h = bh & 7;
    int d = threadIdx.x;

    float m_i[NCHUNK];
    float Mx = -1e30f;
#pragma unroll
    for (int i = 0; i < NCHUNK; ++i) { m_i[i] = mpart[g * NCHUNK + i]; Mx = fmaxf(Mx, m_i[i]); }
    float S = 0.f, O = 0.f;
#pragma unroll
    for (int i = 0; i < NCHUNK; ++i) {
        float w = __expf(m_i[i] - Mx);
        S += w * spart[g * NCHUNK + i];
        O += w * Opart[((size_t)g * NCHUNK + i) * DD + d];
    }
    int qi = TopIdx[g];
    out[((size_t)b * LL + qi) * HD + h * DD + d] = O / S;
}

extern "C" void kernel_launch(void* const* d_in, const int* in_sizes, int n_in,
                              void* d_out, int out_size, void* d_ws, size_t ws_size,
                              hipStream_t stream) {
    const float* Q  = (const float*)d_in[0];
    const float* K  = (const float*)d_in[1];
    const float* V  = (const float*)d_in[2];
    const int*   IS = (const int*)d_in[3];
    float* out = (float*)d_out;
    char* ws = (char*)d_ws;

    float* M      = (float*)(ws + OFF_M);
    int*   TopIdx = (int*)(ws + OFF_TOP);
    float* Vpart  = (float*)(ws + OFF_VPART);
    float* mpart  = (float*)(ws + OFF_MPART);
    float* spart  = (float*)(ws + OFF_SPART);
    float* Opart  = (float*)(ws + OFF_OPART);

    kA_sample_scores<<<BB * LL, 128, 0, stream>>>(Q, K, IS, M);
    kC_vmean<<<BB * HH * 8, 256, 0, stream>>>(V, Vpart);
    kB_topk<<<BB * HH, 256, 0, stream>>>(M, TopIdx);
    kD_fill<<<(BB * LL * HD) / (256 * 4), 256, 0, stream>>>(Vpart, out);
    kE_attn_partial<<<dim3(NCHUNK, BB * HH), 256, 0, stream>>>(Q, K, V, TopIdx,
                                                               Opart, mpart, spart);
    kF_combine<<<BB * HH * UU, 64, 0, stream>>>(Opart, mpart, spart, TopIdx, out);
}

// Round 5
// 286.920 us; speedup vs baseline: 1.8091x; 1.5043x over previous
//
#include <hip/hip_runtime.h>
#include <hip/hip_bf16.h>

// Problem constants (B,L,H,D) = (8,2048,8,64); sample_k = u = 40.
#define BB 8
#define LL 2048
#define HH 8
#define DD 64
#define HD 512      // H*D
#define SK 40       // sample_k
#define UU 40       // top-u
#define NCHUNK 16   // key chunks for flash-decode
#define CHUNK 128   // keys per chunk

// ---------------- workspace layout (bytes) ----------------
static const size_t OFF_M     = 0;                 // B*H*L floats   = 512 KB
static const size_t OFF_TOP   = 512ull * 1024;     // B*H*40 ints    = 10 KB
static const size_t OFF_VPART = 592ull * 1024;     // 8*B*H*64 floats= 128 KB
static const size_t OFF_MPART = 768ull * 1024;     // B*H*40*16      = 160 KB
static const size_t OFF_SPART = 960ull * 1024;     // B*H*40*16      = 160 KB
static const size_t OFF_OPART = 1152ull * 1024;    // B*H*40*16*64   = 10 MB

// ============ kernel A: M[b,h,q] = max_s(Q.Ksample) - mean_s(Q.Ksample) ============
// ROUND-1 VERSION (proven 90 us, VGPR=32). block = 128 = 8 heads x 16 lanes.
__global__ __launch_bounds__(128) void kA_sample_scores(
    const float* __restrict__ Q, const float* __restrict__ K,
    const int* __restrict__ IS, float* __restrict__ M)
{
    int blk = blockIdx.x;            // b*L + q
    int b = blk >> 11;
    int q = blk & (LL - 1);
    int tid = threadIdx.x;
    int h = tid >> 4;
    int lane = tid & 15;

    __shared__ int sidx[SK];
    if (tid < SK) sidx[tid] = IS[q * SK + tid];
    __syncthreads();

    size_t base = (size_t)b * LL * HD;
    const float4 qv = *(const float4*)(Q + base + (size_t)q * HD + h * DD + lane * 4);

    float mx = -1e30f, sm = 0.f;
#pragma unroll 8
    for (int s = 0; s < SK; ++s) {
        int idx = sidx[s];
        const float4 kv = *(const float4*)(K + base + (size_t)idx * HD + h * DD + lane * 4);
        float p = qv.x * kv.x + qv.y * kv.y + qv.z * kv.z + qv.w * kv.w;
        p += __shfl_xor(p, 1);
        p += __shfl_xor(p, 2);
        p += __shfl_xor(p, 4);
        p += __shfl_xor(p, 8);
        mx = fmaxf(mx, p);
        sm += p;
    }
    if (lane == 0)
        M[((size_t)(b * HH + h)) * LL + q] = mx - sm * (1.0f / SK);
}

// ============ kernel B: top-40 of M[bh,:] via 3-level parallel radix select ============
// L1: bits 31:20, L2: bits 19:8, L3: bits 7:0. Every level fully parallel; only
// exact-32-bit-key ties (vanishingly rare) hit a tiny serial loop.
__global__ __launch_bounds__(256) void kB_topk(
    const float* __restrict__ M, int* __restrict__ TopIdx)
{
    int bh = blockIdx.x;
    int tid = threadIdx.x;
    __shared__ unsigned keys[LL];        // 8 KB
    __shared__ int      hist[4096];      // 16 KB
    __shared__ int      sscan[256];      // 1 KB
    __shared__ unsigned ckeyA[2048];     // 8 KB
    __shared__ int      cidxA[2048];     // 8 KB
    __shared__ unsigned ckeyB[2048];     // 8 KB
    __shared__ int      cidxB[2048];     // 8 KB
    __shared__ int ctr[8]; // 0:sel 1:nA 2:nB 3:T 4:kprime 5:nExact

    const float* __restrict__ m = M + (size_t)bh * LL;
    for (int i = tid; i < 4096; i += 256) hist[i] = 0;
    if (tid < 8) ctr[tid] = 0;
    __syncthreads();

    // ---- L1 histogram ----
    for (int i = tid; i < LL; i += 256) {
        unsigned u = __float_as_uint(m[i]);
        u = (u & 0x80000000u) ? ~u : (u | 0x80000000u);   // monotone key
        keys[i] = u;
        atomicAdd(&hist[u >> 20], 1);
    }
    __syncthreads();
    // ---- L1 scan (target UU) ----
    {
        int p = 0;
#pragma unroll
        for (int j = 0; j < 16; ++j) p += hist[tid * 16 + j];
        sscan[tid] = p;
        __syncthreads();
        for (int o = 1; o < 256; o <<= 1) {
            int v = (tid + o < 256) ? sscan[tid + o] : 0;
            __syncthreads();
            sscan[tid] += v;
            __syncthreads();
        }
        int snext = (tid < 255) ? sscan[tid + 1] : 0;
        if (sscan[tid] >= UU && snext < UU) {
            int cum = snext;
            for (int bkt = tid * 16 + 15; bkt >= tid * 16; --bkt) {
                int c = hist[bkt];
                if (cum + c >= UU) { ctr[3] = bkt; ctr[4] = UU - cum; break; }
                cum += c;
            }
        }
    }
    __syncthreads();
    unsigned T1 = (unsigned)ctr[3];
    int k1 = ctr[4];
    // ---- L1 pass: select / collect candidates ----
    for (int i = tid; i < LL; i += 256) {
        unsigned u = keys[i];
        unsigned bkt = u >> 20;
        if (bkt > T1) {
            int p = atomicAdd(&ctr[0], 1);
            TopIdx[bh * UU + p] = i;
        } else if (bkt == T1) {
            int p = atomicAdd(&ctr[1], 1);
            ckeyA[p] = u; cidxA[p] = i;
        }
    }
    __syncthreads();
    int nA = ctr[1];

    // ---- L2 histogram over candidates (bits 19:8) ----
    for (int i = tid; i < 4096; i += 256) hist[i] = 0;
    __syncthreads();
    for (int i = tid; i < nA; i += 256)
        atomicAdd(&hist[(ckeyA[i] >> 8) & 0xFFF], 1);
    __syncthreads();
    // ---- L2 scan (target k1) ----
    {
        int p = 0;
#pragma unroll
        for (int j = 0; j < 16; ++j) p += hist[tid * 16 + j];
        sscan[tid] = p;
        __syncthreads();
        for (int o = 1; o < 256; o <<= 1) {
            int v = (tid + o < 256) ? sscan[tid + o] : 0;
            __syncthreads();
            sscan[tid] += v;
            __syncthreads();
        }
        int snext = (tid < 255) ? sscan[tid + 1] : 0;
        if (sscan[tid] >= k1 && snext < k1) {
            int cum = snext;
            for (int bkt = tid * 16 + 15; bkt >= tid * 16; --bkt) {
                int c = hist[bkt];
                if (cum + c >= k1) { ctr[3] = bkt; ctr[4] = k1 - cum; break; }
                cum += c;
            }
        }
    }
    __syncthreads();
    unsigned T2 = (unsigned)ctr[3];
    int k2 = ctr[4];
    // ---- L2 pass ----
    for (int i = tid; i < nA; i += 256) {
        unsigned u = ckeyA[i];
        unsigned bkt = (u >> 8) & 0xFFF;
        if (bkt > T2) {
            int p = atomicAdd(&ctr[0], 1);
            TopIdx[bh * UU + p] = cidxA[i];
        } else if (bkt == T2) {
            int p = atomicAdd(&ctr[2], 1);
            ckeyB[p] = u; cidxB[p] = cidxA[i];
        }
    }
    __syncthreads();
    int nB = ctr[2];

    // ---- L3 histogram over candidates (bits 7:0, 256 buckets) ----
    for (int i = tid; i < 256; i += 256) hist[i] = 0;
    __syncthreads();
    for (int i = tid; i < nB; i += 256)
        atomicAdd(&hist[ckeyB[i] & 0xFF], 1);
    __syncthreads();
    // ---- L3 scan (target k2), one bucket per thread ----
    {
        sscan[tid] = hist[tid];
        __syncthreads();
        for (int o = 1; o < 256; o <<= 1) {
            int v = (tid + o < 256) ? sscan[tid + o] : 0;
            __syncthreads();
            sscan[tid] += v;
            __syncthreads();
        }
        int snext = (tid < 255) ? sscan[tid + 1] : 0;
        if (sscan[tid] >= k2 && snext < k2) { ctr[3] = tid; ctr[4] = k2 - snext; }
    }
    __syncthreads();
    unsigned T3 = (unsigned)ctr[3];
    int k3 = ctr[4];
    // ---- L3 pass ----
    for (int i = tid; i < nB; i += 256) {
        unsigned u = ckeyB[i];
        unsigned bkt = u & 0xFF;
        if (bkt > T3) {
            int p = atomicAdd(&ctr[0], 1);
            TopIdx[bh * UU + p] = cidxB[i];
        } else if (bkt == T3) {           // exact 32-bit key == threshold key
            int p = atomicAdd(&ctr[5], 1);
            cidxA[p] = cidxB[i];
        }
    }
    __syncthreads();
    // ---- exact-key ties: pick k3 smallest indices (n is ~1 in practice) ----
    if (tid == 0) {
        int n = ctr[5];
        int basep = ctr[0];
        for (int r = 0; r < k3; ++r) {
            int bi = 1 << 30, bp = -1;
            for (int j = 0; j < n; ++j) {
                int id = cidxA[j];
                if (id >= 0 && id < bi) { bi = id; bp = j; }
            }
            TopIdx[bh * UU + basep + r] = bi;
            cidxA[bp] = -1;
        }
    }
}

// ============ kernel C: V partial column-sums (float4 coalesced) ============
__global__ __launch_bounds__(256) void kC_vmean(
    const float* __restrict__ V, float* __restrict__ Vpart)
{
    int bh = blockIdx.x >> 3;
    int ch = blockIdx.x & 7;
    int b = bh >> 3, h = bh & 7;
    int tid = threadIdx.x;
    int dq = tid & 15;           // float4 column group (d = dq*4)
    int lg = tid >> 4;           // 16 row groups

    float4 acc = make_float4(0.f, 0.f, 0.f, 0.f);
    size_t base = ((size_t)b * LL + ch * 256) * HD + h * DD + dq * 4;
    for (int l = lg; l < 256; l += 16) {
        float4 v = *(const float4*)(V + base + (size_t)l * HD);
        acc.x += v.x; acc.y += v.y; acc.z += v.z; acc.w += v.w;
    }
    __shared__ float4 red[256];
    red[tid] = acc;
    __syncthreads();
    if (tid < 16) {
        float4 s = make_float4(0.f, 0.f, 0.f, 0.f);
#pragma unroll
        for (int g = 0; g < 16; ++g) {
            float4 v = red[g * 16 + tid];
            s.x += v.x; s.y += v.y; s.z += v.z; s.w += v.w;
        }
        *(float4*)(Vpart + ch * 4096 + bh * 64 + tid * 4) = s;
    }
}

// ============ kernel D: fill all output rows with mean(V)/L ============
__global__ __launch_bounds__(256) void kD_fill(
    const float* __restrict__ Vpart, float* __restrict__ out)
{
    size_t i4 = (size_t)blockIdx.x * 256 + threadIdx.x;
    size_t o = i4 * 4;
    int hd = (int)(o & (HD - 1));
    int b  = (int)(o >> 20);
    int h  = hd >> 6;
    int idx = (b * HH + h) * DD + (hd & 63);
    float4 acc = make_float4(0.f, 0.f, 0.f, 0.f);
#pragma unroll
    for (int c = 0; c < 8; ++c) {
        float4 v = *(const float4*)(Vpart + c * 4096 + idx);
        acc.x += v.x; acc.y += v.y; acc.z += v.z; acc.w += v.w;
    }
    const float sc = 1.0f / LL;
    float4 r; r.x = acc.x * sc; r.y = acc.y * sc; r.z = acc.z * sc; r.w = acc.w * sc;
    *(float4*)(out + o) = r;
}

// ============ kernel E v4: flash-decode partials, PV loads batched 8-deep ============
// grid = (NCHUNK, B*H), block 256. K rows -> regs (8-deep batches), V rows ->
// 8-deep batched global float4 loads (latency hidden). LDS ~31.7 KB.
__global__ __launch_bounds__(256) void kE_attn_partial(
    const float* __restrict__ Q, const float* __restrict__ K, const float* __restrict__ V,
    const int* __restrict__ TopIdx,
    float* __restrict__ Opart, float* __restrict__ mpart, float* __restrict__ spart)
{
    int c  = blockIdx.x;
    int bh = blockIdx.y;
    int b = bh >> 3, h = bh & 7;
    int tid = threadIdx.x;

    __shared__ float Qs[UU * DD];          // 10 KB
    __shared__ float P[CHUNK * 41];        // 21 KB; bank-safe (stride 41)
    __shared__ int   qidx[UU];
    __shared__ float mred[UU], sred[UU];

    if (tid < UU) qidx[tid] = TopIdx[bh * UU + tid];
    __syncthreads();

    size_t hbase  = (size_t)b * LL * HD + h * DD;
    size_t kcbase = hbase + (size_t)c * CHUNK * HD;

    // stage gathered Q rows (40x64)
    for (int r = tid; r < UU * 16; r += 256) {
        int u = r >> 4, j = r & 15;
        *(float4*)(Qs + u * DD + j * 4) =
            *(const float4*)(Q + hbase + (size_t)qidx[u] * HD + j * 4);
    }
    __syncthreads();

    // ---- scores: thread (l = tid&127, ug = tid>>7); 20 u per thread ----
    {
        int l = tid & (CHUNK - 1), ug = tid >> 7;
        const float* __restrict__ Krow = K + kcbase + (size_t)l * HD;
        float dot[20];
#pragma unroll
        for (int i = 0; i < 20; ++i) dot[i] = 0.f;

#pragma unroll
        for (int half = 0; half < 2; ++half) {
            float4 kr[8];
#pragma unroll
            for (int j = 0; j < 8; ++j)
                kr[j] = *(const float4*)(Krow + half * 32 + j * 4);
#pragma unroll
            for (int j = 0; j < 8; ++j) {
                float4 kv = kr[j];
#pragma unroll
                for (int uu = 0; uu < 20; ++uu) {
                    float4 qv = *(const float4*)(Qs + (ug * 20 + uu) * DD + half * 32 + j * 4);
                    dot[uu] += kv.x * qv.x + kv.y * qv.y + kv.z * qv.z + kv.w * qv.w;
                }
            }
        }
#pragma unroll
        for (int uu = 0; uu < 20; ++uu)
            P[l * 41 + ug * 20 + uu] = dot[uu] * 0.125f;   // 1/sqrt(64)
    }
    __syncthreads();

    // ---- per-u chunk max (40 u x 4 parts of 32 l = 160 threads) ----
    if (tid < UU * 4) {
        int u = tid >> 2, part = tid & 3;
        float m = -1e30f;
        for (int l = part * 32; l < part * 32 + 32; ++l) m = fmaxf(m, P[l * 41 + u]);
        m = fmaxf(m, __shfl_xor(m, 1));
        m = fmaxf(m, __shfl_xor(m, 2));
        if (part == 0) mred[u] = m;
    }
    __syncthreads();
    // ---- exp + per-u chunk sum ----
    if (tid < UU * 4) {
        int u = tid >> 2, part = tid & 3;
        float m = mred[u];
        float s = 0.f;
        for (int l = part * 32; l < part * 32 + 32; ++l) {
            float p = __expf(P[l * 41 + u] - m);
            P[l * 41 + u] = p;
            s += p;
        }
        s += __shfl_xor(s, 1);
        s += __shfl_xor(s, 2);
        if (part == 0) sred[u] = s;
    }
    __syncthreads();

    // ---- PV: thread (dq = tid&15 -> d=dq*4, ug4 = tid>>4); u = ug4 + 16i ----
    // V loads batched 8-deep: 8 independent dwordx4 in flight per wave.
    {
        int dq = tid & 15, ug4 = tid >> 4;
        float4 acc[3];
#pragma unroll
        for (int i = 0; i < 3; ++i) acc[i] = make_float4(0.f, 0.f, 0.f, 0.f);
        const float* __restrict__ Vb = V + kcbase + dq * 4;
        for (int l0 = 0; l0 < CHUNK; l0 += 8) {
            float4 v[8];
#pragma unroll
            for (int j = 0; j < 8; ++j)
                v[j] = *(const float4*)(Vb + (size_t)(l0 + j) * HD);
#pragma unroll
            for (int j = 0; j < 8; ++j) {
#pragma unroll
                for (int i = 0; i < 3; ++i) {
                    int u = ug4 + 16 * i;
                    if (u < UU) {
                        float p = P[(l0 + j) * 41 + u];
                        acc[i].x += p * v[j].x; acc[i].y += p * v[j].y;
                        acc[i].z += p * v[j].z; acc[i].w += p * v[j].w;
                    }
                }
            }
        }
#pragma unroll
        for (int i = 0; i < 3; ++i) {
            int u = ug4 + 16 * i;
            if (u < UU) {
                size_t ob = (((size_t)(bh * UU + u)) * NCHUNK + c) * DD + dq * 4;
                *(float4*)(Opart + ob) = acc[i];
            }
        }
    }
    if (tid < UU) {
        mpart[(bh * UU + tid) * NCHUNK + c] = mred[tid];
        spart[(bh * UU + tid) * NCHUNK + c] = sred[tid];
    }
}

// ============ kernel F: combine chunk partials, scatter into output ============
__global__ __launch_bounds__(64) void kF_combine(
    const float* __restrict__ Opart, const float* __restrict__ mpart,
    const float* __restrict__ spart, const int* __restrict__ TopIdx,
    float* __restrict__ out)
{
    int g = blockIdx.x;            // bh*40 + u
    int bh = g / UU;
    int b = bh >> 3, h = bh & 7;
    int d = threadIdx.x;

    float m_i[NCHUNK];
    float Mx = -1e30f;
#pragma unroll
    for (int i = 0; i < NCHUNK; ++i) { m_i[i] = mpart[g * NCHUNK + i]; Mx = fmaxf(Mx, m_i[i]); }
    float S = 0.f, O = 0.f;
#pragma unroll
    for (int i = 0; i < NCHUNK; ++i) {
        float w = __expf(m_i[i] - Mx);
        S += w * spart[g * NCHUNK + i];
        O += w * Opart[((size_t)g * NCHUNK + i) * DD + d];
    }
    int qi = TopIdx[g];
    out[((size_t)b * LL + qi) * HD + h * DD + d] = O / S;
}

extern "C" void kernel_launch(void* const* d_in, const int* in_sizes, int n_in,
                              void* d_out, int out_size, void* d_ws, size_t ws_size,
                              hipStream_t stream) {
    const float* Q  = (const float*)d_in[0];
    const float* K  = (const float*)d_in[1];
    const float* V  = (const float*)d_in[2];
    const int*   IS = (const int*)d_in[3];
    float* out = (float*)d_out;
    char* ws = (char*)d_ws;

    float* M      = (float*)(ws + OFF_M);
    int*   TopIdx = (int*)(ws + OFF_TOP);
    float* Vpart  = (float*)(ws + OFF_VPART);
    float* mpart  = (float*)(ws + OFF_MPART);
    float* spart  = (float*)(ws + OFF_SPART);
    float* Opart  = (float*)(ws + OFF_OPART);

    kA_sample_scores<<<BB * LL, 128, 0, stream>>>(Q, K, IS, M);
    kC_vmean<<<BB * HH * 8, 256, 0, stream>>>(V, Vpart);
    kB_topk<<<BB * HH, 256, 0, stream>>>(M, TopIdx);
    kD_fill<<<(BB * LL * HD) / (256 * 4), 256, 0, stream>>>(Vpart, out);
    kE_attn_partial<<<dim3(NCHUNK, BB * HH), 256, 0, stream>>>(Q, K, V, TopIdx,
                                                               Opart, mpart, spart);
    kF_combine<<<BB * HH * UU, 64, 0, stream>>>(Opart, mpart, spart, TopIdx, out);
}

// Round 6
// 269.308 us; speedup vs baseline: 1.9274x; 1.0654x over previous
//
#include <hip/hip_runtime.h>
#include <hip/hip_bf16.h>

// Problem constants (B,L,H,D) = (8,2048,8,64); sample_k = u = 40.
#define BB 8
#define LL 2048
#define HH 8
#define DD 64
#define HD 512      // H*D
#define SK 40       // sample_k
#define UU 40       // top-u
#define NCHUNK 16   // key chunks for flash-decode
#define CHUNK 128   // keys per chunk

typedef float v4f __attribute__((ext_vector_type(4)));

// ---------------- workspace layout (bytes) ----------------
static const size_t OFF_M     = 0;                 // B*H*L floats   = 512 KB
static const size_t OFF_TOP   = 512ull * 1024;     // B*H*40 ints    = 10 KB
static const size_t OFF_VPART = 592ull * 1024;     // 8*B*H*64 floats= 128 KB
static const size_t OFF_MPART = 768ull * 1024;     // B*H*40*16      = 160 KB
static const size_t OFF_SPART = 960ull * 1024;     // B*H*40*16      = 160 KB
static const size_t OFF_OPART = 1152ull * 1024;    // B*H*40*16*64   = 10 MB

// ============ kernel A v2: M[b,h,q] = max_s - mean_s of Q.Ksample ============
// block = 128 = 8 heads x 16 lanes. ONE change vs proven round-1 version:
// XCD-pinning (b = blk&7 -> batch b lives on XCD b, K[b]=4MB == L2) and
// nontemporal Q load so the once-read Q stream doesn't evict K from L2.
__global__ __launch_bounds__(128) void kA_sample_scores(
    const float* __restrict__ Q, const float* __restrict__ K,
    const int* __restrict__ IS, float* __restrict__ M)
{
    int blk = blockIdx.x;
    int b = blk & 7;                 // XCD pin: HW round-robins blockIdx % 8
    int q = blk >> 3;
    int tid = threadIdx.x;
    int h = tid >> 4;
    int lane = tid & 15;

    __shared__ int sidx[SK];
    if (tid < SK) sidx[tid] = IS[q * SK + tid];
    __syncthreads();

    size_t base = (size_t)b * LL * HD;
    // nontemporal: Q row is read exactly once ever; keep it out of L2
    v4f qv = __builtin_nontemporal_load(
        (const v4f*)(Q + base + (size_t)q * HD + h * DD + lane * 4));

    float mx = -1e30f, sm = 0.f;
#pragma unroll 8
    for (int s = 0; s < SK; ++s) {
        int idx = sidx[s];
        const float4 kv = *(const float4*)(K + base + (size_t)idx * HD + h * DD + lane * 4);
        float p = qv.x * kv.x + qv.y * kv.y + qv.z * kv.z + qv.w * kv.w;
        p += __shfl_xor(p, 1);
        p += __shfl_xor(p, 2);
        p += __shfl_xor(p, 4);
        p += __shfl_xor(p, 8);
        mx = fmaxf(mx, p);
        sm += p;
    }
    if (lane == 0)
        M[((size_t)(b * HH + h)) * LL + q] = mx - sm * (1.0f / SK);
}

// ============ kernel B: top-40 of M[bh,:] via 3-level parallel radix select ============
__global__ __launch_bounds__(256) void kB_topk(
    const float* __restrict__ M, int* __restrict__ TopIdx)
{
    int bh = blockIdx.x;
    int tid = threadIdx.x;
    __shared__ unsigned keys[LL];        // 8 KB
    __shared__ int      hist[4096];      // 16 KB
    __shared__ int      sscan[256];      // 1 KB
    __shared__ unsigned ckeyA[2048];     // 8 KB
    __shared__ int      cidxA[2048];     // 8 KB
    __shared__ unsigned ckeyB[2048];     // 8 KB
    __shared__ int      cidxB[2048];     // 8 KB
    __shared__ int ctr[8]; // 0:sel 1:nA 2:nB 3:T 4:kprime 5:nExact

    const float* __restrict__ m = M + (size_t)bh * LL;
    for (int i = tid; i < 4096; i += 256) hist[i] = 0;
    if (tid < 8) ctr[tid] = 0;
    __syncthreads();

    // ---- L1 histogram (bits 31:20) ----
    for (int i = tid; i < LL; i += 256) {
        unsigned u = __float_as_uint(m[i]);
        u = (u & 0x80000000u) ? ~u : (u | 0x80000000u);   // monotone key
        keys[i] = u;
        atomicAdd(&hist[u >> 20], 1);
    }
    __syncthreads();
    // ---- L1 scan (target UU) ----
    {
        int p = 0;
#pragma unroll
        for (int j = 0; j < 16; ++j) p += hist[tid * 16 + j];
        sscan[tid] = p;
        __syncthreads();
        for (int o = 1; o < 256; o <<= 1) {
            int v = (tid + o < 256) ? sscan[tid + o] : 0;
            __syncthreads();
            sscan[tid] += v;
            __syncthreads();
        }
        int snext = (tid < 255) ? sscan[tid + 1] : 0;
        if (sscan[tid] >= UU && snext < UU) {
            int cum = snext;
            for (int bkt = tid * 16 + 15; bkt >= tid * 16; --bkt) {
                int c = hist[bkt];
                if (cum + c >= UU) { ctr[3] = bkt; ctr[4] = UU - cum; break; }
                cum += c;
            }
        }
    }
    __syncthreads();
    unsigned T1 = (unsigned)ctr[3];
    int k1 = ctr[4];
    // ---- L1 pass ----
    for (int i = tid; i < LL; i += 256) {
        unsigned u = keys[i];
        unsigned bkt = u >> 20;
        if (bkt > T1) {
            int p = atomicAdd(&ctr[0], 1);
            TopIdx[bh * UU + p] = i;
        } else if (bkt == T1) {
            int p = atomicAdd(&ctr[1], 1);
            ckeyA[p] = u; cidxA[p] = i;
        }
    }
    __syncthreads();
    int nA = ctr[1];

    // ---- L2 histogram (bits 19:8) ----
    for (int i = tid; i < 4096; i += 256) hist[i] = 0;
    __syncthreads();
    for (int i = tid; i < nA; i += 256)
        atomicAdd(&hist[(ckeyA[i] >> 8) & 0xFFF], 1);
    __syncthreads();
    // ---- L2 scan (target k1) ----
    {
        int p = 0;
#pragma unroll
        for (int j = 0; j < 16; ++j) p += hist[tid * 16 + j];
        sscan[tid] = p;
        __syncthreads();
        for (int o = 1; o < 256; o <<= 1) {
            int v = (tid + o < 256) ? sscan[tid + o] : 0;
            __syncthreads();
            sscan[tid] += v;
            __syncthreads();
        }
        int snext = (tid < 255) ? sscan[tid + 1] : 0;
        if (sscan[tid] >= k1 && snext < k1) {
            int cum = snext;
            for (int bkt = tid * 16 + 15; bkt >= tid * 16; --bkt) {
                int c = hist[bkt];
                if (cum + c >= k1) { ctr[3] = bkt; ctr[4] = k1 - cum; break; }
                cum += c;
            }
        }
    }
    __syncthreads();
    unsigned T2 = (unsigned)ctr[3];
    int k2 = ctr[4];
    // ---- L2 pass ----
    for (int i = tid; i < nA; i += 256) {
        unsigned u = ckeyA[i];
        unsigned bkt = (u >> 8) & 0xFFF;
        if (bkt > T2) {
            int p = atomicAdd(&ctr[0], 1);
            TopIdx[bh * UU + p] = cidxA[i];
        } else if (bkt == T2) {
            int p = atomicAdd(&ctr[2], 1);
            ckeyB[p] = u; cidxB[p] = cidxA[i];
        }
    }
    __syncthreads();
    int nB = ctr[2];

    // ---- L3 histogram (bits 7:0) ----
    for (int i = tid; i < 256; i += 256) hist[i] = 0;
    __syncthreads();
    for (int i = tid; i < nB; i += 256)
        atomicAdd(&hist[ckeyB[i] & 0xFF], 1);
    __syncthreads();
    // ---- L3 scan (target k2) ----
    {
        sscan[tid] = hist[tid];
        __syncthreads();
        for (int o = 1; o < 256; o <<= 1) {
            int v = (tid + o < 256) ? sscan[tid + o] : 0;
            __syncthreads();
            sscan[tid] += v;
            __syncthreads();
        }
        int snext = (tid < 255) ? sscan[tid + 1] : 0;
        if (sscan[tid] >= k2 && snext < k2) { ctr[3] = tid; ctr[4] = k2 - snext; }
    }
    __syncthreads();
    unsigned T3 = (unsigned)ctr[3];
    int k3 = ctr[4];
    // ---- L3 pass ----
    for (int i = tid; i < nB; i += 256) {
        unsigned u = ckeyB[i];
        unsigned bkt = u & 0xFF;
        if (bkt > T3) {
            int p = atomicAdd(&ctr[0], 1);
            TopIdx[bh * UU + p] = cidxB[i];
        } else if (bkt == T3) {
            int p = atomicAdd(&ctr[5], 1);
            cidxA[p] = cidxB[i];
        }
    }
    __syncthreads();
    // ---- exact-key ties: pick k3 smallest indices ----
    if (tid == 0) {
        int n = ctr[5];
        int basep = ctr[0];
        for (int r = 0; r < k3; ++r) {
            int bi = 1 << 30, bp = -1;
            for (int j = 0; j < n; ++j) {
                int id = cidxA[j];
                if (id >= 0 && id < bi) { bi = id; bp = j; }
            }
            TopIdx[bh * UU + basep + r] = bi;
            cidxA[bp] = -1;
        }
    }
}

// ============ kernel C: V partial column-sums (float4 coalesced) ============
__global__ __launch_bounds__(256) void kC_vmean(
    const float* __restrict__ V, float* __restrict__ Vpart)
{
    int bh = blockIdx.x >> 3;
    int ch = blockIdx.x & 7;
    int b = bh >> 3, h = bh & 7;
    int tid = threadIdx.x;
    int dq = tid & 15;
    int lg = tid >> 4;

    float4 acc = make_float4(0.f, 0.f, 0.f, 0.f);
    size_t base = ((size_t)b * LL + ch * 256) * HD + h * DD + dq * 4;
    for (int l = lg; l < 256; l += 16) {
        float4 v = *(const float4*)(V + base + (size_t)l * HD);
        acc.x += v.x; acc.y += v.y; acc.z += v.z; acc.w += v.w;
    }
    __shared__ float4 red[256];
    red[tid] = acc;
    __syncthreads();
    if (tid < 16) {
        float4 s = make_float4(0.f, 0.f, 0.f, 0.f);
#pragma unroll
        for (int g = 0; g < 16; ++g) {
            float4 v = red[g * 16 + tid];
            s.x += v.x; s.y += v.y; s.z += v.z; s.w += v.w;
        }
        *(float4*)(Vpart + ch * 4096 + bh * 64 + tid * 4) = s;
    }
}

// ============ kernel D: fill all output rows with mean(V)/L ============
__global__ __launch_bounds__(256) void kD_fill(
    const float* __restrict__ Vpart, float* __restrict__ out)
{
    size_t i4 = (size_t)blockIdx.x * 256 + threadIdx.x;
    size_t o = i4 * 4;
    int hd = (int)(o & (HD - 1));
    int b  = (int)(o >> 20);
    int h  = hd >> 6;
    int idx = (b * HH + h) * DD + (hd & 63);
    float4 acc = make_float4(0.f, 0.f, 0.f, 0.f);
#pragma unroll
    for (int c = 0; c < 8; ++c) {
        float4 v = *(const float4*)(Vpart + c * 4096 + idx);
        acc.x += v.x; acc.y += v.y; acc.z += v.z; acc.w += v.w;
    }
    const float sc = 1.0f / LL;
    float4 r; r.x = acc.x * sc; r.y = acc.y * sc; r.z = acc.z * sc; r.w = acc.w * sc;
    *(float4*)(out + o) = r;
}

// ============ kernel E v4: flash-decode partials, PV loads batched 8-deep ============
__global__ __launch_bounds__(256) void kE_attn_partial(
    const float* __restrict__ Q, const float* __restrict__ K, const float* __restrict__ V,
    const int* __restrict__ TopIdx,
    float* __restrict__ Opart, float* __restrict__ mpart, float* __restrict__ spart)
{
    int c  = blockIdx.x;
    int bh = blockIdx.y;
    int b = bh >> 3, h = bh & 7;
    int tid = threadIdx.x;

    __shared__ float Qs[UU * DD];          // 10 KB
    __shared__ float P[CHUNK * 41];        // 21 KB; bank-safe (stride 41)
    __shared__ int   qidx[UU];
    __shared__ float mred[UU], sred[UU];

    if (tid < UU) qidx[tid] = TopIdx[bh * UU + tid];
    __syncthreads();

    size_t hbase  = (size_t)b * LL * HD + h * DD;
    size_t kcbase = hbase + (size_t)c * CHUNK * HD;

    for (int r = tid; r < UU * 16; r += 256) {
        int u = r >> 4, j = r & 15;
        *(float4*)(Qs + u * DD + j * 4) =
            *(const float4*)(Q + hbase + (size_t)qidx[u] * HD + j * 4);
    }
    __syncthreads();

    // ---- scores ----
    {
        int l = tid & (CHUNK - 1), ug = tid >> 7;
        const float* __restrict__ Krow = K + kcbase + (size_t)l * HD;
        float dot[20];
#pragma unroll
        for (int i = 0; i < 20; ++i) dot[i] = 0.f;

#pragma unroll
        for (int half = 0; half < 2; ++half) {
            float4 kr[8];
#pragma unroll
            for (int j = 0; j < 8; ++j)
                kr[j] = *(const float4*)(Krow + half * 32 + j * 4);
#pragma unroll
            for (int j = 0; j < 8; ++j) {
                float4 kv = kr[j];
#pragma unroll
                for (int uu = 0; uu < 20; ++uu) {
                    float4 qv = *(const float4*)(Qs + (ug * 20 + uu) * DD + half * 32 + j * 4);
                    dot[uu] += kv.x * qv.x + kv.y * qv.y + kv.z * qv.z + kv.w * qv.w;
                }
            }
        }
#pragma unroll
        for (int uu = 0; uu < 20; ++uu)
            P[l * 41 + ug * 20 + uu] = dot[uu] * 0.125f;   // 1/sqrt(64)
    }
    __syncthreads();

    // ---- per-u chunk max ----
    if (tid < UU * 4) {
        int u = tid >> 2, part = tid & 3;
        float m = -1e30f;
        for (int l = part * 32; l < part * 32 + 32; ++l) m = fmaxf(m, P[l * 41 + u]);
        m = fmaxf(m, __shfl_xor(m, 1));
        m = fmaxf(m, __shfl_xor(m, 2));
        if (part == 0) mred[u] = m;
    }
    __syncthreads();
    // ---- exp + per-u chunk sum ----
    if (tid < UU * 4) {
        int u = tid >> 2, part = tid & 3;
        float m = mred[u];
        float s = 0.f;
        for (int l = part * 32; l < part * 32 + 32; ++l) {
            float p = __expf(P[l * 41 + u] - m);
            P[l * 41 + u] = p;
            s += p;
        }
        s += __shfl_xor(s, 1);
        s += __shfl_xor(s, 2);
        if (part == 0) sred[u] = s;
    }
    __syncthreads();

    // ---- PV: V loads batched 8-deep ----
    {
        int dq = tid & 15, ug4 = tid >> 4;
        float4 acc[3];
#pragma unroll
        for (int i = 0; i < 3; ++i) acc[i] = make_float4(0.f, 0.f, 0.f, 0.f);
        const float* __restrict__ Vb = V + kcbase + dq * 4;
        for (int l0 = 0; l0 < CHUNK; l0 += 8) {
            float4 v[8];
#pragma unroll
            for (int j = 0; j < 8; ++j)
                v[j] = *(const float4*)(Vb + (size_t)(l0 + j) * HD);
#pragma unroll
            for (int j = 0; j < 8; ++j) {
#pragma unroll
                for (int i = 0; i < 3; ++i) {
                    int u = ug4 + 16 * i;
                    if (u < UU) {
                        float p = P[(l0 + j) * 41 + u];
                        acc[i].x += p * v[j].x; acc[i].y += p * v[j].y;
                        acc[i].z += p * v[j].z; acc[i].w += p * v[j].w;
                    }
                }
            }
        }
#pragma unroll
        for (int i = 0; i < 3; ++i) {
            int u = ug4 + 16 * i;
            if (u < UU) {
                size_t ob = (((size_t)(bh * UU + u)) * NCHUNK + c) * DD + dq * 4;
                *(float4*)(Opart + ob) = acc[i];
            }
        }
    }
    if (tid < UU) {
        mpart[(bh * UU + tid) * NCHUNK + c] = mred[tid];
        spart[(bh * UU + tid) * NCHUNK + c] = sred[tid];
    }
}

// ============ kernel F: combine chunk partials, scatter into output ============
__global__ __launch_bounds__(64) void kF_combine(
    const float* __restrict__ Opart, const float* __restrict__ mpart,
    const float* __restrict__ spart, const int* __restrict__ TopIdx,
    float* __restrict__ out)
{
    int g = blockIdx.x;            // bh*40 + u
    int bh = g / UU;
    int b = bh >> 3, h = bh & 7;
    int d = threadIdx.x;

    float m_i[NCHUNK];
    float Mx = -1e30f;
#pragma unroll
    for (int i = 0; i < NCHUNK; ++i) { m_i[i] = mpart[g * NCHUNK + i]; Mx = fmaxf(Mx, m_i[i]); }
    float S = 0.f, O = 0.f;
#pragma unroll
    for (int i = 0; i < NCHUNK; ++i) {
        float w = __expf(m_i[i] - Mx);
        S += w * spart[g * NCHUNK + i];
        O += w * Opart[((size_t)g * NCHUNK + i) * DD + d];
    }
    int qi = TopIdx[g];
    out[((size_t)b * LL + qi) * HD + h * DD + d] = O / S;
}

extern "C" void kernel_launch(void* const* d_in, const int* in_sizes, int n_in,
                              void* d_out, int out_size, void* d_ws, size_t ws_size,
                              hipStream_t stream) {
    const float* Q  = (const float*)d_in[0];
    const float* K  = (const float*)d_in[1];
    const float* V  = (const float*)d_in[2];
    const int*   IS = (const int*)d_in[3];
    float* out = (float*)d_out;
    char* ws = (char*)d_ws;

    float* M      = (float*)(ws + OFF_M);
    int*   TopIdx = (int*)(ws + OFF_TOP);
    float* Vpart  = (float*)(ws + OFF_VPART);
    float* mpart  = (float*)(ws + OFF_MPART);
    float* spart  = (float*)(ws + OFF_SPART);
    float* Opart  = (float*)(ws + OFF_OPART);

    kA_sample_scores<<<BB * LL, 128, 0, stream>>>(Q, K, IS, M);
    kC_vmean<<<BB * HH * 8, 256, 0, stream>>>(V, Vpart);
    kB_topk<<<BB * HH, 256, 0, stream>>>(M, TopIdx);
    kD_fill<<<(BB * LL * HD) / (256 * 4), 256, 0, stream>>>(Vpart, out);
    kE_attn_partial<<<dim3(NCHUNK, BB * HH), 256, 0, stream>>>(Q, K, V, TopIdx,
                                                               Opart, mpart, spart);
    kF_combine<<<BB * HH * UU, 64, 0, stream>>>(Opart, mpart, spart, TopIdx, out);
}

// Round 8
// 263.479 us; speedup vs baseline: 1.9701x; 1.0221x over previous
//
#include <hip/hip_runtime.h>
#include <hip/hip_bf16.h>

// Problem constants (B,L,H,D) = (8,2048,8,64); sample_k = u = 40.
#define BB 8
#define LL 2048
#define HH 8
#define DD 64
#define HD 512      // H*D
#define SK 40       // sample_k
#define UU 40       // top-u
#define NCHUNK 16   // key chunks for flash-decode
#define CHUNK 128   // keys per chunk

typedef float v4f __attribute__((ext_vector_type(4)));

// ---------------- workspace layout (bytes) ----------------
static const size_t OFF_M     = 0;                 // B*H*L floats   = 512 KB
static const size_t OFF_TOP   = 512ull * 1024;     // B*H*40 ints    = 10 KB
static const size_t OFF_VPART = 592ull * 1024;     // 8*B*H*64 floats= 128 KB
static const size_t OFF_MPART = 768ull * 1024;     // B*H*40*16      = 160 KB
static const size_t OFF_SPART = 960ull * 1024;     // B*H*40*16      = 160 KB
static const size_t OFF_OPART = 1152ull * 1024;    // B*H*40*16*64   = 10 MB

// butterfly-add via DPP (VALU pipe) instead of ds_swizzle (LDS pipe).
// dpp_ctrl must be an ICE -> template parameter. Valid within an aligned
// 16-lane row: xor1,xor2 via quad_perm; half/row mirror == xor4/xor8 once
// quads are uniform.
template <int CTRL>
__device__ __forceinline__ float dpp_add(float x) {
    int yi = __builtin_amdgcn_mov_dpp(__float_as_int(x), CTRL, 0xF, 0xF, true);
    return x + __int_as_float(yi);
}

// ============ kernel A v3: M[b,h,q] = max_s - mean_s of Q.Ksample ============
// block = 128 = 8 heads x 16 lanes. vs v2: (1) sample index forced to SGPR
// (scalar addr math, saddr-form loads, no LDS staging/barrier); (2) 16-lane
// dot-reduce via DPP adds instead of ds_swizzle.
__global__ __launch_bounds__(128) void kA_sample_scores(
    const float* __restrict__ Q, const float* __restrict__ K,
    const int* __restrict__ IS, float* __restrict__ M)
{
    int blk = blockIdx.x;
    int b = blk & 7;                 // XCD pin: batch b -> XCD b (K[b]=4MB==L2)
    int q = blk >> 3;
    int tid = threadIdx.x;
    int h = tid >> 4;
    int lane = tid & 15;

    const int* __restrict__ isq = IS + q * SK;   // block-uniform
    size_t base = (size_t)b * LL * HD;
    int off = h * DD + lane * 4;                 // per-thread, constant over s
    v4f qv = __builtin_nontemporal_load(
        (const v4f*)(Q + base + (size_t)q * HD + off));
    const float* __restrict__ Kb = K + base;

    float mx = -1e30f, sm = 0.f;
#pragma unroll 8
    for (int s = 0; s < SK; ++s) {
        int idx = __builtin_amdgcn_readfirstlane(isq[s]);   // SGPR index
        const float* __restrict__ Krow = Kb + (size_t)idx * HD;  // scalar math
        const float4 kv = *(const float4*)(Krow + off);
        float p = qv.x * kv.x + qv.y * kv.y + qv.z * kv.z + qv.w * kv.w;
        p = dpp_add<0xB1>(p);    // quad_perm xor1
        p = dpp_add<0x4E>(p);    // quad_perm xor2
        p = dpp_add<0x141>(p);   // row_half_mirror (== xor4 here)
        p = dpp_add<0x140>(p);   // row_mirror      (== xor8 here)
        mx = fmaxf(mx, p);
        sm += p;
    }
    if (lane == 0)
        M[((size_t)(b * HH + h)) * LL + q] = mx - sm * (1.0f / SK);
}

// ============ kernel B: top-40 of M[bh,:] via 3-level parallel radix select ============
__global__ __launch_bounds__(256) void kB_topk(
    const float* __restrict__ M, int* __restrict__ TopIdx)
{
    int bh = blockIdx.x;
    int tid = threadIdx.x;
    __shared__ unsigned keys[LL];        // 8 KB
    __shared__ int      hist[4096];      // 16 KB
    __shared__ int      sscan[256];      // 1 KB
    __shared__ unsigned ckeyA[2048];     // 8 KB
    __shared__ int      cidxA[2048];     // 8 KB
    __shared__ unsigned ckeyB[2048];     // 8 KB
    __shared__ int      cidxB[2048];     // 8 KB
    __shared__ int ctr[8]; // 0:sel 1:nA 2:nB 3:T 4:kprime 5:nExact

    const float* __restrict__ m = M + (size_t)bh * LL;
    for (int i = tid; i < 4096; i += 256) hist[i] = 0;
    if (tid < 8) ctr[tid] = 0;
    __syncthreads();

    // ---- L1 histogram (bits 31:20) ----
    for (int i = tid; i < LL; i += 256) {
        unsigned u = __float_as_uint(m[i]);
        u = (u & 0x80000000u) ? ~u : (u | 0x80000000u);   // monotone key
        keys[i] = u;
        atomicAdd(&hist[u >> 20], 1);
    }
    __syncthreads();
    // ---- L1 scan (target UU) ----
    {
        int p = 0;
#pragma unroll
        for (int j = 0; j < 16; ++j) p += hist[tid * 16 + j];
        sscan[tid] = p;
        __syncthreads();
        for (int o = 1; o < 256; o <<= 1) {
            int v = (tid + o < 256) ? sscan[tid + o] : 0;
            __syncthreads();
            sscan[tid] += v;
            __syncthreads();
        }
        int snext = (tid < 255) ? sscan[tid + 1] : 0;
        if (sscan[tid] >= UU && snext < UU) {
            int cum = snext;
            for (int bkt = tid * 16 + 15; bkt >= tid * 16; --bkt) {
                int c = hist[bkt];
                if (cum + c >= UU) { ctr[3] = bkt; ctr[4] = UU - cum; break; }
                cum += c;
            }
        }
    }
    __syncthreads();
    unsigned T1 = (unsigned)ctr[3];
    int k1 = ctr[4];
    // ---- L1 pass ----
    for (int i = tid; i < LL; i += 256) {
        unsigned u = keys[i];
        unsigned bkt = u >> 20;
        if (bkt > T1) {
            int p = atomicAdd(&ctr[0], 1);
            TopIdx[bh * UU + p] = i;
        } else if (bkt == T1) {
            int p = atomicAdd(&ctr[1], 1);
            ckeyA[p] = u; cidxA[p] = i;
        }
    }
    __syncthreads();
    int nA = ctr[1];

    // ---- L2 histogram (bits 19:8) ----
    for (int i = tid; i < 4096; i += 256) hist[i] = 0;
    __syncthreads();
    for (int i = tid; i < nA; i += 256)
        atomicAdd(&hist[(ckeyA[i] >> 8) & 0xFFF], 1);
    __syncthreads();
    // ---- L2 scan (target k1) ----
    {
        int p = 0;
#pragma unroll
        for (int j = 0; j < 16; ++j) p += hist[tid * 16 + j];
        sscan[tid] = p;
        __syncthreads();
        for (int o = 1; o < 256; o <<= 1) {
            int v = (tid + o < 256) ? sscan[tid + o] : 0;
            __syncthreads();
            sscan[tid] += v;
            __syncthreads();
        }
        int snext = (tid < 255) ? sscan[tid + 1] : 0;
        if (sscan[tid] >= k1 && snext < k1) {
            int cum = snext;
            for (int bkt = tid * 16 + 15; bkt >= tid * 16; --bkt) {
                int c = hist[bkt];
                if (cum + c >= k1) { ctr[3] = bkt; ctr[4] = k1 - cum; break; }
                cum += c;
            }
        }
    }
    __syncthreads();
    unsigned T2 = (unsigned)ctr[3];
    int k2 = ctr[4];
    // ---- L2 pass ----
    for (int i = tid; i < nA; i += 256) {
        unsigned u = ckeyA[i];
        unsigned bkt = (u >> 8) & 0xFFF;
        if (bkt > T2) {
            int p = atomicAdd(&ctr[0], 1);
            TopIdx[bh * UU + p] = cidxA[i];
        } else if (bkt == T2) {
            int p = atomicAdd(&ctr[2], 1);
            ckeyB[p] = u; cidxB[p] = cidxA[i];
        }
    }
    __syncthreads();
    int nB = ctr[2];

    // ---- L3 histogram (bits 7:0) ----
    for (int i = tid; i < 256; i += 256) hist[i] = 0;
    __syncthreads();
    for (int i = tid; i < nB; i += 256)
        atomicAdd(&hist[ckeyB[i] & 0xFF], 1);
    __syncthreads();
    // ---- L3 scan (target k2) ----
    {
        sscan[tid] = hist[tid];
        __syncthreads();
        for (int o = 1; o < 256; o <<= 1) {
            int v = (tid + o < 256) ? sscan[tid + o] : 0;
            __syncthreads();
            sscan[tid] += v;
            __syncthreads();
        }
        int snext = (tid < 255) ? sscan[tid + 1] : 0;
        if (sscan[tid] >= k2 && snext < k2) { ctr[3] = tid; ctr[4] = k2 - snext; }
    }
    __syncthreads();
    unsigned T3 = (unsigned)ctr[3];
    int k3 = ctr[4];
    // ---- L3 pass ----
    for (int i = tid; i < nB; i += 256) {
        unsigned u = ckeyB[i];
        unsigned bkt = u & 0xFF;
        if (bkt > T3) {
            int p = atomicAdd(&ctr[0], 1);
            TopIdx[bh * UU + p] = cidxB[i];
        } else if (bkt == T3) {
            int p = atomicAdd(&ctr[5], 1);
            cidxA[p] = cidxB[i];
        }
    }
    __syncthreads();
    // ---- exact-key ties: pick k3 smallest indices ----
    if (tid == 0) {
        int n = ctr[5];
        int basep = ctr[0];
        for (int r = 0; r < k3; ++r) {
            int bi = 1 << 30, bp = -1;
            for (int j = 0; j < n; ++j) {
                int id = cidxA[j];
                if (id >= 0 && id < bi) { bi = id; bp = j; }
            }
            TopIdx[bh * UU + basep + r] = bi;
            cidxA[bp] = -1;
        }
    }
}

// ============ kernel C: V partial column-sums (float4 coalesced) ============
__global__ __launch_bounds__(256) void kC_vmean(
    const float* __restrict__ V, float* __restrict__ Vpart)
{
    int bh = blockIdx.x >> 3;
    int ch = blockIdx.x & 7;
    int b = bh >> 3, h = bh & 7;
    int tid = threadIdx.x;
    int dq = tid & 15;
    int lg = tid >> 4;

    float4 acc = make_float4(0.f, 0.f, 0.f, 0.f);
    size_t base = ((size_t)b * LL + ch * 256) * HD + h * DD + dq * 4;
    for (int l = lg; l < 256; l += 16) {
        float4 v = *(const float4*)(V + base + (size_t)l * HD);
        acc.x += v.x; acc.y += v.y; acc.z += v.z; acc.w += v.w;
    }
    __shared__ float4 red[256];
    red[tid] = acc;
    __syncthreads();
    if (tid < 16) {
        float4 s = make_float4(0.f, 0.f, 0.f, 0.f);
#pragma unroll
        for (int g = 0; g < 16; ++g) {
            float4 v = red[g * 16 + tid];
            s.x += v.x; s.y += v.y; s.z += v.z; s.w += v.w;
        }
        *(float4*)(Vpart + ch * 4096 + bh * 64 + tid * 4) = s;
    }
}

// ============ kernel D: fill all output rows with mean(V)/L ============
__global__ __launch_bounds__(256) void kD_fill(
    const float* __restrict__ Vpart, float* __restrict__ out)
{
    size_t i4 = (size_t)blockIdx.x * 256 + threadIdx.x;
    size_t o = i4 * 4;
    int hd = (int)(o & (HD - 1));
    int b  = (int)(o >> 20);
    int h  = hd >> 6;
    int idx = (b * HH + h) * DD + (hd & 63);
    float4 acc = make_float4(0.f, 0.f, 0.f, 0.f);
#pragma unroll
    for (int c = 0; c < 8; ++c) {
        float4 v = *(const float4*)(Vpart + c * 4096 + idx);
        acc.x += v.x; acc.y += v.y; acc.z += v.z; acc.w += v.w;
    }
    const float sc = 1.0f / LL;
    float4 r; r.x = acc.x * sc; r.y = acc.y * sc; r.z = acc.z * sc; r.w = acc.w * sc;
    *(float4*)(out + o) = r;
}

// ============ kernel E v4: flash-decode partials, PV loads batched 8-deep ============
__global__ __launch_bounds__(256) void kE_attn_partial(
    const float* __restrict__ Q, const float* __restrict__ K, const float* __restrict__ V,
    const int* __restrict__ TopIdx,
    float* __restrict__ Opart, float* __restrict__ mpart, float* __restrict__ spart)
{
    int c  = blockIdx.x;
    int bh = blockIdx.y;
    int b = bh >> 3, h = bh & 7;
    int tid = threadIdx.x;

    __shared__ float Qs[UU * DD];          // 10 KB
    __shared__ float P[CHUNK * 41];        // 21 KB; bank-safe (stride 41)
    __shared__ int   qidx[UU];
    __shared__ float mred[UU], sred[UU];

    if (tid < UU) qidx[tid] = TopIdx[bh * UU + tid];
    __syncthreads();

    size_t hbase  = (size_t)b * LL * HD + h * DD;
    size_t kcbase = hbase + (size_t)c * CHUNK * HD;

    for (int r = tid; r < UU * 16; r += 256) {
        int u = r >> 4, j = r & 15;
        *(float4*)(Qs + u * DD + j * 4) =
            *(const float4*)(Q + hbase + (size_t)qidx[u] * HD + j * 4);
    }
    __syncthreads();

    // ---- scores ----
    {
        int l = tid & (CHUNK - 1), ug = tid >> 7;
        const float* __restrict__ Krow = K + kcbase + (size_t)l * HD;
        float dot[20];
#pragma unroll
        for (int i = 0; i < 20; ++i) dot[i] = 0.f;

#pragma unroll
        for (int half = 0; half < 2; ++half) {
            float4 kr[8];
#pragma unroll
            for (int j = 0; j < 8; ++j)
                kr[j] = *(const float4*)(Krow + half * 32 + j * 4);
#pragma unroll
            for (int j = 0; j < 8; ++j) {
                float4 kv = kr[j];
#pragma unroll
                for (int uu = 0; uu < 20; ++uu) {
                    float4 qv = *(const float4*)(Qs + (ug * 20 + uu) * DD + half * 32 + j * 4);
                    dot[uu] += kv.x * qv.x + kv.y * qv.y + kv.z * qv.z + kv.w * qv.w;
                }
            }
        }
#pragma unroll
        for (int uu = 0; uu < 20; ++uu)
            P[l * 41 + ug * 20 + uu] = dot[uu] * 0.125f;   // 1/sqrt(64)
    }
    __syncthreads();

    // ---- per-u chunk max ----
    if (tid < UU * 4) {
        int u = tid >> 2, part = tid & 3;
        float m = -1e30f;
        for (int l = part * 32; l < part * 32 + 32; ++l) m = fmaxf(m, P[l * 41 + u]);
        m = fmaxf(m, __shfl_xor(m, 1));
        m = fmaxf(m, __shfl_xor(m, 2));
        if (part == 0) mred[u] = m;
    }
    __syncthreads();
    // ---- exp + per-u chunk sum ----
    if (tid < UU * 4) {
        int u = tid >> 2, part = tid & 3;
        float m = mred[u];
        float s = 0.f;
        for (int l = part * 32; l < part * 32 + 32; ++l) {
            float p = __expf(P[l * 41 + u] - m);
            P[l * 41 + u] = p;
            s += p;
        }
        s += __shfl_xor(s, 1);
        s += __shfl_xor(s, 2);
        if (part == 0) sred[u] = s;
    }
    __syncthreads();

    // ---- PV: V loads batched 8-deep ----
    {
        int dq = tid & 15, ug4 = tid >> 4;
        float4 acc[3];
#pragma unroll
        for (int i = 0; i < 3; ++i) acc[i] = make_float4(0.f, 0.f, 0.f, 0.f);
        const float* __restrict__ Vb = V + kcbase + dq * 4;
        for (int l0 = 0; l0 < CHUNK; l0 += 8) {
            float4 v[8];
#pragma unroll
            for (int j = 0; j < 8; ++j)
                v[j] = *(const float4*)(Vb + (size_t)(l0 + j) * HD);
#pragma unroll
            for (int j = 0; j < 8; ++j) {
#pragma unroll
                for (int i = 0; i < 3; ++i) {
                    int u = ug4 + 16 * i;
                    if (u < UU) {
                        float p = P[(l0 + j) * 41 + u];
                        acc[i].x += p * v[j].x; acc[i].y += p * v[j].y;
                        acc[i].z += p * v[j].z; acc[i].w += p * v[j].w;
                    }
                }
            }
        }
#pragma unroll
        for (int i = 0; i < 3; ++i) {
            int u = ug4 + 16 * i;
            if (u < UU) {
                size_t ob = (((size_t)(bh * UU + u)) * NCHUNK + c) * DD + dq * 4;
                *(float4*)(Opart + ob) = acc[i];
            }
        }
    }
    if (tid < UU) {
        mpart[(bh * UU + tid) * NCHUNK + c] = mred[tid];
        spart[(bh * UU + tid) * NCHUNK + c] = sred[tid];
    }
}

// ============ kernel F: combine chunk partials, scatter into output ============
__global__ __launch_bounds__(64) void kF_combine(
    const float* __restrict__ Opart, const float* __restrict__ mpart,
    const float* __restrict__ spart, const int* __restrict__ TopIdx,
    float* __restrict__ out)
{
    int g = blockIdx.x;            // bh*40 + u
    int bh = g / UU;
    int b = bh >> 3, h = bh & 7;
    int d = threadIdx.x;

    float m_i[NCHUNK];
    float Mx = -1e30f;
#pragma unroll
    for (int i = 0; i < NCHUNK; ++i) { m_i[i] = mpart[g * NCHUNK + i]; Mx = fmaxf(Mx, m_i[i]); }
    float S = 0.f, O = 0.f;
#pragma unroll
    for (int i = 0; i < NCHUNK; ++i) {
        float w = __expf(m_i[i] - Mx);
        S += w * spart[g * NCHUNK + i];
        O += w * Opart[((size_t)g * NCHUNK + i) * DD + d];
    }
    int qi = TopIdx[g];
    out[((size_t)b * LL + qi) * HD + h * DD + d] = O / S;
}

extern "C" void kernel_launch(void* const* d_in, const int* in_sizes, int n_in,
                              void* d_out, int out_size, void* d_ws, size_t ws_size,
                              hipStream_t stream) {
    const float* Q  = (const float*)d_in[0];
    const float* K  = (const float*)d_in[1];
    const float* V  = (const float*)d_in[2];
    const int*   IS = (const int*)d_in[3];
    float* out = (float*)d_out;
    char* ws = (char*)d_ws;

    float* M      = (float*)(ws + OFF_M);
    int*   TopIdx = (int*)(ws + OFF_TOP);
    float* Vpart  = (float*)(ws + OFF_VPART);
    float* mpart  = (float*)(ws + OFF_MPART);
    float* spart  = (float*)(ws + OFF_SPART);
    float* Opart  = (float*)(ws + OFF_OPART);

    kA_sample_scores<<<BB * LL, 128, 0, stream>>>(Q, K, IS, M);
    kC_vmean<<<BB * HH * 8, 256, 0, stream>>>(V, Vpart);
    kB_topk<<<BB * HH, 256, 0, stream>>>(M, TopIdx);
    kD_fill<<<(BB * LL * HD) / (256 * 4), 256, 0, stream>>>(Vpart, out);
    kE_attn_partial<<<dim3(NCHUNK, BB * HH), 256, 0, stream>>>(Q, K, V, TopIdx,
                                                               Opart, mpart, spart);
    kF_combine<<<BB * HH * UU, 64, 0, stream>>>(Opart, mpart, spart, TopIdx, out);
}

// Round 9
// 254.825 us; speedup vs baseline: 2.0370x; 1.0340x over previous
//
#include <hip/hip_runtime.h>
#include <hip/hip_bf16.h>

// Problem constants (B,L,H,D) = (8,2048,8,64); sample_k = u = 40.
#define BB 8
#define LL 2048
#define HH 8
#define DD 64
#define HD 512      // H*D
#define SK 40       // sample_k
#define UU 40       // top-u
#define NCHUNK 16   // key chunks for flash-decode
#define CHUNK 128   // keys per chunk

typedef float v4f __attribute__((ext_vector_type(4)));

// ---------------- workspace layout (bytes) ----------------
static const size_t OFF_M     = 0;                 // B*H*L floats   = 512 KB
static const size_t OFF_TOP   = 512ull * 1024;     // B*H*40 ints    = 10 KB
static const size_t OFF_VPART = 592ull * 1024;     // 8*B*H*64 floats= 128 KB
static const size_t OFF_MPART = 768ull * 1024;     // B*H*40*16      = 160 KB
static const size_t OFF_SPART = 960ull * 1024;     // B*H*40*16      = 160 KB
static const size_t OFF_OPART = 1152ull * 1024;    // B*H*40*16*64   = 10 MB

// butterfly-add via DPP (VALU pipe). ctrl must be an ICE -> template param.
template <int CTRL>
__device__ __forceinline__ float dpp_add(float x) {
    int yi = __builtin_amdgcn_mov_dpp(__float_as_int(x), CTRL, 0xF, 0xF, true);
    return x + __int_as_float(yi);
}

// ============ kernel A v3.1: M[b,h,q] = max_s - mean_s of Q.Ksample ============
// block = 128 = 8 heads x 16 lanes. Scalar (SGPR) index addressing, DPP
// 16-lane dot-reduce, XCD pinning. v3.1: unroll 16 for deeper gather MLP.
__global__ __launch_bounds__(128) void kA_sample_scores(
    const float* __restrict__ Q, const float* __restrict__ K,
    const int* __restrict__ IS, float* __restrict__ M)
{
    int blk = blockIdx.x;
    int b = blk & 7;                 // XCD pin: batch b -> XCD b (K[b]=4MB==L2)
    int q = blk >> 3;
    int tid = threadIdx.x;
    int h = tid >> 4;
    int lane = tid & 15;

    const int* __restrict__ isq = IS + q * SK;   // block-uniform
    size_t base = (size_t)b * LL * HD;
    int off = h * DD + lane * 4;                 // per-thread, constant over s
    v4f qv = __builtin_nontemporal_load(
        (const v4f*)(Q + base + (size_t)q * HD + off));
    const float* __restrict__ Kb = K + base;

    float mx = -1e30f, sm = 0.f;
#pragma unroll 16
    for (int s = 0; s < SK; ++s) {
        int idx = __builtin_amdgcn_readfirstlane(isq[s]);   // SGPR index
        const float* __restrict__ Krow = Kb + (size_t)idx * HD;  // scalar math
        const float4 kv = *(const float4*)(Krow + off);
        float p = qv.x * kv.x + qv.y * kv.y + qv.z * kv.z + qv.w * kv.w;
        p = dpp_add<0xB1>(p);    // quad_perm xor1
        p = dpp_add<0x4E>(p);    // quad_perm xor2
        p = dpp_add<0x141>(p);   // row_half_mirror (== xor4 here)
        p = dpp_add<0x140>(p);   // row_mirror      (== xor8 here)
        mx = fmaxf(mx, p);
        sm += p;
    }
    if (lane == 0)
        M[((size_t)(b * HH + h)) * LL + q] = mx - sm * (1.0f / SK);
}

// ============ kernel B: top-40 of M[bh,:] via 3-level parallel radix select ============
__global__ __launch_bounds__(256) void kB_topk(
    const float* __restrict__ M, int* __restrict__ TopIdx)
{
    int bh = blockIdx.x;
    int tid = threadIdx.x;
    __shared__ unsigned keys[LL];        // 8 KB
    __shared__ int      hist[4096];      // 16 KB
    __shared__ int      sscan[256];      // 1 KB
    __shared__ unsigned ckeyA[2048];     // 8 KB
    __shared__ int      cidxA[2048];     // 8 KB
    __shared__ unsigned ckeyB[2048];     // 8 KB
    __shared__ int      cidxB[2048];     // 8 KB
    __shared__ int ctr[8]; // 0:sel 1:nA 2:nB 3:T 4:kprime 5:nExact

    const float* __restrict__ m = M + (size_t)bh * LL;
    for (int i = tid; i < 4096; i += 256) hist[i] = 0;
    if (tid < 8) ctr[tid] = 0;
    __syncthreads();

    // ---- L1 histogram (bits 31:20) ----
    for (int i = tid; i < LL; i += 256) {
        unsigned u = __float_as_uint(m[i]);
        u = (u & 0x80000000u) ? ~u : (u | 0x80000000u);   // monotone key
        keys[i] = u;
        atomicAdd(&hist[u >> 20], 1);
    }
    __syncthreads();
    // ---- L1 scan (target UU) ----
    {
        int p = 0;
#pragma unroll
        for (int j = 0; j < 16; ++j) p += hist[tid * 16 + j];
        sscan[tid] = p;
        __syncthreads();
        for (int o = 1; o < 256; o <<= 1) {
            int v = (tid + o < 256) ? sscan[tid + o] : 0;
            __syncthreads();
            sscan[tid] += v;
            __syncthreads();
        }
        int snext = (tid < 255) ? sscan[tid + 1] : 0;
        if (sscan[tid] >= UU && snext < UU) {
            int cum = snext;
            for (int bkt = tid * 16 + 15; bkt >= tid * 16; --bkt) {
                int c = hist[bkt];
                if (cum + c >= UU) { ctr[3] = bkt; ctr[4] = UU - cum; break; }
                cum += c;
            }
        }
    }
    __syncthreads();
    unsigned T1 = (unsigned)ctr[3];
    int k1 = ctr[4];
    // ---- L1 pass ----
    for (int i = tid; i < LL; i += 256) {
        unsigned u = keys[i];
        unsigned bkt = u >> 20;
        if (bkt > T1) {
            int p = atomicAdd(&ctr[0], 1);
            TopIdx[bh * UU + p] = i;
        } else if (bkt == T1) {
            int p = atomicAdd(&ctr[1], 1);
            ckeyA[p] = u; cidxA[p] = i;
        }
    }
    __syncthreads();
    int nA = ctr[1];

    // ---- L2 histogram (bits 19:8) ----
    for (int i = tid; i < 4096; i += 256) hist[i] = 0;
    __syncthreads();
    for (int i = tid; i < nA; i += 256)
        atomicAdd(&hist[(ckeyA[i] >> 8) & 0xFFF], 1);
    __syncthreads();
    // ---- L2 scan (target k1) ----
    {
        int p = 0;
#pragma unroll
        for (int j = 0; j < 16; ++j) p += hist[tid * 16 + j];
        sscan[tid] = p;
        __syncthreads();
        for (int o = 1; o < 256; o <<= 1) {
            int v = (tid + o < 256) ? sscan[tid + o] : 0;
            __syncthreads();
            sscan[tid] += v;
            __syncthreads();
        }
        int snext = (tid < 255) ? sscan[tid + 1] : 0;
        if (sscan[tid] >= k1 && snext < k1) {
            int cum = snext;
            for (int bkt = tid * 16 + 15; bkt >= tid * 16; --bkt) {
                int c = hist[bkt];
                if (cum + c >= k1) { ctr[3] = bkt; ctr[4] = k1 - cum; break; }
                cum += c;
            }
        }
    }
    __syncthreads();
    unsigned T2 = (unsigned)ctr[3];
    int k2 = ctr[4];
    // ---- L2 pass ----
    for (int i = tid; i < nA; i += 256) {
        unsigned u = ckeyA[i];
        unsigned bkt = (u >> 8) & 0xFFF;
        if (bkt > T2) {
            int p = atomicAdd(&ctr[0], 1);
            TopIdx[bh * UU + p] = cidxA[i];
        } else if (bkt == T2) {
            int p = atomicAdd(&ctr[2], 1);
            ckeyB[p] = u; cidxB[p] = cidxA[i];
        }
    }
    __syncthreads();
    int nB = ctr[2];

    // ---- L3 histogram (bits 7:0) ----
    for (int i = tid; i < 256; i += 256) hist[i] = 0;
    __syncthreads();
    for (int i = tid; i < nB; i += 256)
        atomicAdd(&hist[ckeyB[i] & 0xFF], 1);
    __syncthreads();
    // ---- L3 scan (target k2) ----
    {
        sscan[tid] = hist[tid];
        __syncthreads();
        for (int o = 1; o < 256; o <<= 1) {
            int v = (tid + o < 256) ? sscan[tid + o] : 0;
            __syncthreads();
            sscan[tid] += v;
            __syncthreads();
        }
        int snext = (tid < 255) ? sscan[tid + 1] : 0;
        if (sscan[tid] >= k2 && snext < k2) { ctr[3] = tid; ctr[4] = k2 - snext; }
    }
    __syncthreads();
    unsigned T3 = (unsigned)ctr[3];
    int k3 = ctr[4];
    // ---- L3 pass ----
    for (int i = tid; i < nB; i += 256) {
        unsigned u = ckeyB[i];
        unsigned bkt = u & 0xFF;
        if (bkt > T3) {
            int p = atomicAdd(&ctr[0], 1);
            TopIdx[bh * UU + p] = cidxB[i];
        } else if (bkt == T3) {
            int p = atomicAdd(&ctr[5], 1);
            cidxA[p] = cidxB[i];
        }
    }
    __syncthreads();
    // ---- exact-key ties: pick k3 smallest indices ----
    if (tid == 0) {
        int n = ctr[5];
        int basep = ctr[0];
        for (int r = 0; r < k3; ++r) {
            int bi = 1 << 30, bp = -1;
            for (int j = 0; j < n; ++j) {
                int id = cidxA[j];
                if (id >= 0 && id < bi) { bi = id; bp = j; }
            }
            TopIdx[bh * UU + basep + r] = bi;
            cidxA[bp] = -1;
        }
    }
}

// ============ kernel C: V partial column-sums (float4 coalesced) ============
__global__ __launch_bounds__(256) void kC_vmean(
    const float* __restrict__ V, float* __restrict__ Vpart)
{
    int bh = blockIdx.x >> 3;
    int ch = blockIdx.x & 7;
    int b = bh >> 3, h = bh & 7;
    int tid = threadIdx.x;
    int dq = tid & 15;
    int lg = tid >> 4;

    float4 acc = make_float4(0.f, 0.f, 0.f, 0.f);
    size_t base = ((size_t)b * LL + ch * 256) * HD + h * DD + dq * 4;
    for (int l = lg; l < 256; l += 16) {
        float4 v = *(const float4*)(V + base + (size_t)l * HD);
        acc.x += v.x; acc.y += v.y; acc.z += v.z; acc.w += v.w;
    }
    __shared__ float4 red[256];
    red[tid] = acc;
    __syncthreads();
    if (tid < 16) {
        float4 s = make_float4(0.f, 0.f, 0.f, 0.f);
#pragma unroll
        for (int g = 0; g < 16; ++g) {
            float4 v = red[g * 16 + tid];
            s.x += v.x; s.y += v.y; s.z += v.z; s.w += v.w;
        }
        *(float4*)(Vpart + ch * 4096 + bh * 64 + tid * 4) = s;
    }
}

// ============ kernel D: fill all output rows with mean(V)/L ============
__global__ __launch_bounds__(256) void kD_fill(
    const float* __restrict__ Vpart, float* __restrict__ out)
{
    size_t i4 = (size_t)blockIdx.x * 256 + threadIdx.x;
    size_t o = i4 * 4;
    int hd = (int)(o & (HD - 1));
    int b  = (int)(o >> 20);
    int h  = hd >> 6;
    int idx = (b * HH + h) * DD + (hd & 63);
    float4 acc = make_float4(0.f, 0.f, 0.f, 0.f);
#pragma unroll
    for (int c = 0; c < 8; ++c) {
        float4 v = *(const float4*)(Vpart + c * 4096 + idx);
        acc.x += v.x; acc.y += v.y; acc.z += v.z; acc.w += v.w;
    }
    const float sc = 1.0f / LL;
    float4 r; r.x = acc.x * sc; r.y = acc.y * sc; r.z = acc.z * sc; r.w = acc.w * sc;
    *(float4*)(out + o) = r;
}

// ============ kernel E v5: flash-decode partials, in-register softmax ============
// grid = (NCHUNK, B*H), block 256. Score dots stay in registers; per-u max and
// sum are done with wave shfl reductions + a 2-entry cross-wave LDS combine;
// P is written to LDS already exponentiated. No strided max/exp phases, no
// bank conflicts, all 256 threads active.
__global__ __launch_bounds__(256) void kE_attn_partial(
    const float* __restrict__ Q, const float* __restrict__ K, const float* __restrict__ V,
    const int* __restrict__ TopIdx,
    float* __restrict__ Opart, float* __restrict__ mpart, float* __restrict__ spart)
{
    int c  = blockIdx.x;
    int bh = blockIdx.y;
    int b = bh >> 3, h = bh & 7;
    int tid = threadIdx.x;

    __shared__ float Qs[UU * DD];          // 10 KB
    __shared__ float P[CHUNK * 41];        // 21 KB; bank-safe (stride 41)
    __shared__ int   qidx[UU];
    __shared__ float wmax[2][UU];          // cross-wave max combine
    __shared__ float wsum[2][UU];          // cross-wave sum combine
    __shared__ float mred[UU], sred[UU];

    if (tid < UU) qidx[tid] = TopIdx[bh * UU + tid];
    __syncthreads();

    size_t hbase  = (size_t)b * LL * HD + h * DD;
    size_t kcbase = hbase + (size_t)c * CHUNK * HD;

    for (int r = tid; r < UU * 16; r += 256) {
        int u = r >> 4, j = r & 15;
        *(float4*)(Qs + u * DD + j * 4) =
            *(const float4*)(Q + hbase + (size_t)qidx[u] * HD + j * 4);
    }
    __syncthreads();

    // ---- scores + in-register softmax ----
    {
        int l = tid & (CHUNK - 1), ug = tid >> 7;   // ug in {0,1}: u = ug*20+uu
        int pair = (tid >> 6) & 1;                  // which wave of the l-range
        const float* __restrict__ Krow = K + kcbase + (size_t)l * HD;
        float dot[20];
#pragma unroll
        for (int i = 0; i < 20; ++i) dot[i] = 0.f;

#pragma unroll
        for (int half = 0; half < 2; ++half) {
            float4 kr[8];
#pragma unroll
            for (int j = 0; j < 8; ++j)
                kr[j] = *(const float4*)(Krow + half * 32 + j * 4);
#pragma unroll
            for (int j = 0; j < 8; ++j) {
                float4 kv = kr[j];
#pragma unroll
                for (int uu = 0; uu < 20; ++uu) {
                    float4 qv = *(const float4*)(Qs + (ug * 20 + uu) * DD + half * 32 + j * 4);
                    dot[uu] += kv.x * qv.x + kv.y * qv.y + kv.z * qv.z + kv.w * qv.w;
                }
            }
        }

        // scale + wave-level max per u (64 lanes = 64 l's of this wave)
        float wm[20];
#pragma unroll
        for (int uu = 0; uu < 20; ++uu) {
            float d = dot[uu] * 0.125f;   // 1/sqrt(64)
            dot[uu] = d;
            float v = d;
            v = fmaxf(v, __shfl_xor(v, 1));
            v = fmaxf(v, __shfl_xor(v, 2));
            v = fmaxf(v, __shfl_xor(v, 4));
            v = fmaxf(v, __shfl_xor(v, 8));
            v = fmaxf(v, __shfl_xor(v, 16));
            v = fmaxf(v, __shfl_xor(v, 32));
            wm[uu] = v;
        }
        if ((tid & 63) == 0) {
#pragma unroll
            for (int uu = 0; uu < 20; ++uu) wmax[pair][ug * 20 + uu] = wm[uu];
        }
        __syncthreads();

        // final max, exp in-register, write exp'd P, wave-level sum
        float ws[20];
#pragma unroll
        for (int uu = 0; uu < 20; ++uu) {
            int u = ug * 20 + uu;
            float m = fmaxf(wmax[0][u], wmax[1][u]);
            float p = __expf(dot[uu] - m);
            dot[uu] = m;                   // stash m for later
            P[l * 41 + u] = p;
            float v = p;
            v += __shfl_xor(v, 1);
            v += __shfl_xor(v, 2);
            v += __shfl_xor(v, 4);
            v += __shfl_xor(v, 8);
            v += __shfl_xor(v, 16);
            v += __shfl_xor(v, 32);
            ws[uu] = v;
        }
        if ((tid & 63) == 0) {
#pragma unroll
            for (int uu = 0; uu < 20; ++uu) wsum[pair][ug * 20 + uu] = ws[uu];
        }
        __syncthreads();

        // one thread per u-half finalizes m,s
        if (tid == 0 || tid == 128) {
#pragma unroll
            for (int uu = 0; uu < 20; ++uu) {
                int u = ug * 20 + uu;
                mred[u] = dot[uu];
                sred[u] = wsum[0][u] + wsum[1][u];
            }
        }
    }
    // P final (written before the wsum barrier) -> PV can start now

    // ---- PV: thread (dq = tid&15 -> d=dq*4, ug4 = tid>>4); u = ug4 + 16i ----
    {
        int dq = tid & 15, ug4 = tid >> 4;
        float4 acc[3];
#pragma unroll
        for (int i = 0; i < 3; ++i) acc[i] = make_float4(0.f, 0.f, 0.f, 0.f);
        const float* __restrict__ Vb = V + kcbase + dq * 4;
        for (int l0 = 0; l0 < CHUNK; l0 += 8) {
            float4 v[8];
#pragma unroll
            for (int j = 0; j < 8; ++j)
                v[j] = *(const float4*)(Vb + (size_t)(l0 + j) * HD);
#pragma unroll
            for (int j = 0; j < 8; ++j) {
#pragma unroll
                for (int i = 0; i < 3; ++i) {
                    int u = ug4 + 16 * i;
                    if (u < UU) {
                        float p = P[(l0 + j) * 41 + u];
                        acc[i].x += p * v[j].x; acc[i].y += p * v[j].y;
                        acc[i].z += p * v[j].z; acc[i].w += p * v[j].w;
                    }
                }
            }
        }
#pragma unroll
        for (int i = 0; i < 3; ++i) {
            int u = ug4 + 16 * i;
            if (u < UU) {
                size_t ob = (((size_t)(bh * UU + u)) * NCHUNK + c) * DD + dq * 4;
                *(float4*)(Opart + ob) = acc[i];
            }
        }
    }
    __syncthreads();   // mred/sred ready
    if (tid < UU) {
        mpart[(bh * UU + tid) * NCHUNK + c] = mred[tid];
        spart[(bh * UU + tid) * NCHUNK + c] = sred[tid];
    }
}

// ============ kernel F: combine chunk partials, scatter into output ============
__global__ __launch_bounds__(64) void kF_combine(
    const float* __restrict__ Opart, const float* __restrict__ mpart,
    const float* __restrict__ spart, const int* __restrict__ TopIdx,
    float* __restrict__ out)
{
    int g = blockIdx.x;            // bh*40 + u
    int bh = g / UU;
    int b = bh >> 3, h = bh & 7;
    int d = threadIdx.x;

    float m_i[NCHUNK];
    float Mx = -1e30f;
#pragma unroll
    for (int i = 0; i < NCHUNK; ++i) { m_i[i] = mpart[g * NCHUNK + i]; Mx = fmaxf(Mx, m_i[i]); }
    float S = 0.f, O = 0.f;
#pragma unroll
    for (int i = 0; i < NCHUNK; ++i) {
        float w = __expf(m_i[i] - Mx);
        S += w * spart[g * NCHUNK + i];
        O += w * Opart[((size_t)g * NCHUNK + i) * DD + d];
    }
    int qi = TopIdx[g];
    out[((size_t)b * LL + qi) * HD + h * DD + d] = O / S;
}

extern "C" void kernel_launch(void* const* d_in, const int* in_sizes, int n_in,
                              void* d_out, int out_size, void* d_ws, size_t ws_size,
                              hipStream_t stream) {
    const float* Q  = (const float*)d_in[0];
    const float* K  = (const float*)d_in[1];
    const float* V  = (const float*)d_in[2];
    const int*   IS = (const int*)d_in[3];
    float* out = (float*)d_out;
    char* ws = (char*)d_ws;

    float* M      = (float*)(ws + OFF_M);
    int*   TopIdx = (int*)(ws + OFF_TOP);
    float* Vpart  = (float*)(ws + OFF_VPART);
    float* mpart  = (float*)(ws + OFF_MPART);
    float* spart  = (float*)(ws + OFF_SPART);
    float* Opart  = (float*)(ws + OFF_OPART);

    kA_sample_scores<<<BB * LL, 128, 0, stream>>>(Q, K, IS, M);
    kC_vmean<<<BB * HH * 8, 256, 0, stream>>>(V, Vpart);
    kB_topk<<<BB * HH, 256, 0, stream>>>(M, TopIdx);
    kD_fill<<<(BB * LL * HD) / (256 * 4), 256, 0, stream>>>(Vpart, out);
    kE_attn_partial<<<dim3(NCHUNK, BB * HH), 256, 0, stream>>>(Q, K, V, TopIdx,
                                                               Opart, mpart, spart);
    kF_combine<<<BB * HH * UU, 64, 0, stream>>>(Opart, mpart, spart, TopIdx, out);
}